// Round 6
// baseline (4790.900 us; speedup 1.0000x reference)
//
#include <hip/hip_runtime.h>
#include <hip/hip_bf16.h>
#include <cstdint>
#include <cstddef>

typedef unsigned short u16;
typedef unsigned long long u64;
typedef short s8v __attribute__((ext_vector_type(8)));
typedef float f4v __attribute__((ext_vector_type(4)));

#define DI __device__ __forceinline__

// ---------- helpers ----------
DI u16 f2bf(float f){ unsigned u = __float_as_uint(f); u += 0x7fffu + ((u>>16)&1u); return (u16)(u>>16); }
DI float bf2f(u16 h){ return __uint_as_float(((unsigned)h)<<16); }
DI int ocol(int pc){ return ((pc>>3)&3)*512 + (pc>>5)*8 + (pc&7); }  // packed col -> original col
// slot layout (gate-contiguous): slot s = hb*32 + jj*4 + g  ->  original col
DI int ocol2(int s){ int pc = (s & ~31) | ((s&3)<<3) | ((s>>2)&7); return ocol(pc); }
DI int pc2slot(int pc){ return (pc & ~31) | ((pc&7)<<2) | ((pc>>3)&3); }
DI float sigm(float x){ x = fminf(fmaxf(x,-30.f),30.f); return 1.f/(1.f+__expf(-x)); }
DI float tanhx(float x){ x = fminf(fmaxf(x,-15.f),15.f); float e = __expf(-2.f*x); return (1.f-e)/(1.f+e); }
DI uint4 packh8(const u16* h){
  uint4 r; r.x=(unsigned)h[0]|((unsigned)h[1]<<16); r.y=(unsigned)h[2]|((unsigned)h[3]<<16);
  r.z=(unsigned)h[4]|((unsigned)h[5]<<16); r.w=(unsigned)h[6]|((unsigned)h[7]<<16); return r;
}
DI void unp8(uint4 w, float* o){
  o[0]=bf2f((u16)(w.x&0xffffu)); o[1]=bf2f((u16)(w.x>>16));
  o[2]=bf2f((u16)(w.y&0xffffu)); o[3]=bf2f((u16)(w.y>>16));
  o[4]=bf2f((u16)(w.z&0xffffu)); o[5]=bf2f((u16)(w.z>>16));
  o[6]=bf2f((u16)(w.w&0xffffu)); o[7]=bf2f((u16)(w.w>>16));
}
DI s8v u4s8(uint4 u){ union{uint4 a; s8v b;} t; t.a=u; return t.b; }

// ---------- agent-coherent (fence-free) access helpers ----------
DI u64 cohld64(const void* p){
  return __hip_atomic_load((const u64*)p, __ATOMIC_RELAXED, __HIP_MEMORY_SCOPE_AGENT);
}
DI uint4 cohld128(const void* p){
  u64 lo = cohld64(p);
  u64 hi = cohld64((const char*)p + 8);
  uint4 r; r.x=(unsigned)lo; r.y=(unsigned)(lo>>32); r.z=(unsigned)hi; r.w=(unsigned)(hi>>32);
  return r;
}
DI f4v cohldf4(const float* p){
  u64 lo = cohld64(p);
  u64 hi = cohld64(p + 2);
  f4v r;
  r[0]=__uint_as_float((unsigned)lo); r[1]=__uint_as_float((unsigned)(lo>>32));
  r[2]=__uint_as_float((unsigned)hi); r[3]=__uint_as_float((unsigned)(hi>>32));
  return r;
}
DI void cohst32(void* p, unsigned v){
  __hip_atomic_store((unsigned*)p, v, __ATOMIC_RELAXED, __HIP_MEMORY_SCOPE_AGENT);
}
DI void cohst64(void* p, u64 v){
  __hip_atomic_store((u64*)p, v, __ATOMIC_RELAXED, __HIP_MEMORY_SCOPE_AGENT);
}

// ---------- small builder kernels ----------
__global__ void k_init(const float* bb, const float* eh, const float* ec,
                       float* bp, float* h2X, float* cst, float* ctxX, unsigned* bar){
  int i = blockIdx.x*256 + threadIdx.x;
  if (i < 2048) bp[i] = bb[ocol2(i)];
  else if (i < 2048+32768) h2X[i-2048] = eh[i-2048];
  else if (i < 2048+65536) cst[i-34816] = ec[i-34816];
  else if (i < 2048+131072) ctxX[i-67584] = 0.f;
  else if (i < 2048+131072+1280) bar[i-133120] = 0u;
}

// hcat = [h0 | zeros] as bf16 hi/lo split, rows b, 1536 cols
__global__ void k_hinit(const float* __restrict__ eh, u16* __restrict__ hhi, u16* __restrict__ hlo){
  int i = blockIdx.x*256 + threadIdx.x; if (i >= 64*1536) return;
  int c = i % 1536;
  float f = (c < 512) ? eh[(i/1536)*512 + c] : 0.f;
  u16 hi = f2bf(f);
  hhi[i] = hi;
  hlo[i] = (c < 512) ? f2bf(f - bf2f(hi)) : (u16)0;
}

__global__ void k_cvt(const float* __restrict__ src, u16* __restrict__ dst, int octs){
  int g = blockIdx.x*256 + threadIdx.x; if (g >= octs) return;
  const float4* p = (const float4*)(src + (size_t)g*8);
  float4 a = p[0], b = p[1];
  u16 h[8] = {f2bf(a.x),f2bf(a.y),f2bf(a.z),f2bf(a.w),f2bf(b.x),f2bf(b.y),f2bf(b.z),f2bf(b.w)};
  *(uint4*)&dst[(size_t)g*8] = packh8(h);
}

__global__ void k_embgather(const int* __restrict__ dec, const float* __restrict__ emb, u16* __restrict__ dst){
  int g = blockIdx.x*256 + threadIdx.x; if (g >= 3776*40) return;
  int row = g/40, o = g%40;
  int b = row & 63, t = row >> 6;
  int tok = dec[b*59 + t];
  u16 h[8];
  #pragma unroll
  for(int j=0;j<8;++j){ int k = o*8+j; float f = (k<300)? emb[(size_t)tok*300 + k] : 0.f; h[j]=f2bf(f); }
  *(uint4*)&dst[(size_t)row*320 + o*8] = packh8(h);
}

__global__ void k_wmT(const float* __restrict__ Wm, u16* __restrict__ dst){
  int g = blockIdx.x*256 + threadIdx.x; if (g >= 512*128) return;
  int hcol = g/128, o = g%128;
  u16 h[8];
  #pragma unroll
  for(int j=0;j<8;++j){ int m = o*8+j; h[j]=f2bf(Wm[(size_t)m*512 + hcol]); }
  *(uint4*)&dst[(size_t)hcol*1024 + o*8] = packh8(h);
}

__global__ void k_waT(const float* __restrict__ Wa, u16* __restrict__ dst){
  int g = blockIdx.x*256 + threadIdx.x; if (g >= 512*192) return;
  int c = g/192, o = g%192;
  u16 h[8];
  #pragma unroll
  for(int j=0;j<8;++j){ int k = o*8+j; h[j]=f2bf(Wa[(size_t)k*512 + c]); }
  *(uint4*)&dst[(size_t)c*1536 + o*8] = packh8(h);
}

// Wx top rows (emb part), cols in slot (gate-contiguous) order -> Zemb lands gate-contiguous
__global__ void k_wxtpT(const float* __restrict__ Wx, u16* __restrict__ dst){
  int g = blockIdx.x*256 + threadIdx.x; if (g >= 2048*40) return;
  int pc = g/40, o = g%40; int oc = ocol2(pc);
  u16 h[8];
  #pragma unroll
  for(int j=0;j<8;++j){ int e = o*8+j; float f = (e<300)? Wx[(size_t)e*2048 + oc] : 0.f; h[j]=f2bf(f); }
  *(uint4*)&dst[(size_t)pc*320 + o*8] = packh8(h);
}

// Wx_att^T splits: segs [hi(512) | hi(512) | lo(512)] along k'  (packed-pc cols)
__global__ void k_wxaT(const float* __restrict__ Wx, u16* __restrict__ dst){
  int g = blockIdx.x*256 + threadIdx.x; if (g >= 2048*192) return;
  int pc = g/192, o = g%192; int oc = ocol(pc);
  u16 h[8];
  #pragma unroll
  for(int j=0;j<8;++j){
    int kp = o*8+j; int seg = kp>>9; int jd = kp&511;
    float f = Wx[(size_t)(300+jd)*2048 + oc];
    u16 hi = f2bf(f);
    h[j] = (seg==2) ? f2bf(f - bf2f(hi)) : hi;
  }
  *(uint4*)&dst[(size_t)pc*1536 + o*8] = packh8(h);
}

// Wa splits (A side of composite GEMM): segs [hi | lo | hi]
__global__ void k_waA(const float* __restrict__ Wa, u16* __restrict__ dst){
  int g = blockIdx.x*256 + threadIdx.x; if (g >= 1536*192) return;
  int r = g/192, o = g%192;
  u16 h[8];
  #pragma unroll
  for(int j=0;j<8;++j){
    int kp = o*8+j; int seg = kp>>9; int jd = kp&511;
    float f = Wa[(size_t)r*512 + jd];
    u16 hi = f2bf(f);
    h[j] = (seg==1) ? f2bf(f - bf2f(hi)) : hi;
  }
  *(uint4*)&dst[(size_t)r*1536 + o*8] = packh8(h);
}

// Uh^T packed splits: phys [hi(512) | lo(512)]
__global__ void k_buhT(const float* __restrict__ Uh, u16* __restrict__ dst){
  int g = blockIdx.x*256 + threadIdx.x; if (g >= 2048*128) return;
  int pc = g/128, o = g%128; int oc = ocol(pc);
  u16 h[8];
  #pragma unroll
  for(int j=0;j<8;++j){
    int kp = o*8+j; int r = kp&511;
    float f = Uh[(size_t)r*2048 + oc];
    u16 hi = f2bf(f);
    h[j] = (kp<512) ? hi : f2bf(f - bf2f(hi));
  }
  *(uint4*)&dst[(size_t)pc*1024 + o*8] = packh8(h);
}

// (WzcT + Uh-on-top)^T splits: phys [hi(1536) | lo(1536)]
__global__ void k_wzcT(const float* __restrict__ wzcT, const float* __restrict__ Uh, u16* __restrict__ dst){
  int g = blockIdx.x*256 + threadIdx.x; if (g >= 2048*384) return;
  int pc = g/384, o = g%384; int oc = ocol(pc);
  u16 h[8];
  #pragma unroll
  for(int j=0;j<8;++j){
    int kp = o*8+j; int r = kp % 1536;
    float f = wzcT[(size_t)pc*1536 + r] + ((r<512) ? Uh[(size_t)r*2048 + oc] : 0.f);
    u16 hi = f2bf(f);
    h[j] = (kp<1536) ? hi : f2bf(f - bf2f(hi));
  }
  *(uint4*)&dst[(size_t)pc*3072 + o*8] = packh8(h);
}

// A2cat = [h2 | ctx] bf16, rows r = t*64+b  (reads slot t+1 == row r+64)
__global__ void k_a2dump(const float* __restrict__ h2X, const float* __restrict__ ctxX, u16* __restrict__ dst){
  int g = blockIdx.x*256 + threadIdx.x; if (g >= 3776*192) return;
  int r = g/192, o = g%192;
  u16 h[8];
  #pragma unroll
  for(int j=0;j<8;++j){
    int k = o*8+j;
    float f = (k<512) ? h2X[(size_t)(r+64)*512 + k] : ctxX[(size_t)(r+64)*1024 + (k-512)];
    h[j] = f2bf(f);
  }
  *(uint4*)&dst[(size_t)r*1536 + o*8] = packh8(h);
}

// Wf [512][34004] f32 -> WfT [34004][512] bf16 (LDS-tiled transpose)
__global__ __launch_bounds__(256) void k_wfT(const float* __restrict__ Wf, u16* __restrict__ WfT){
  __shared__ u16 T[64*72];
  int n0 = blockIdx.x*64, k0 = blockIdx.y*64;
  int tid = threadIdx.x;
  int kl = tid>>2, nq = (tid&3)*16;
  u16 h[16];
  if (n0 + 64 <= 34004){
    const float4* p = (const float4*)(Wf + (size_t)(k0+kl)*34004 + n0 + nq);
    #pragma unroll
    for(int q=0;q<4;++q){ float4 f = p[q]; h[q*4+0]=f2bf(f.x); h[q*4+1]=f2bf(f.y); h[q*4+2]=f2bf(f.z); h[q*4+3]=f2bf(f.w); }
  } else {
    #pragma unroll
    for(int j=0;j<16;++j){ int n = n0+nq+j; float f = (n<34004)? Wf[(size_t)(k0+kl)*34004 + n] : 0.f; h[j]=f2bf(f); }
  }
  *(uint4*)&T[kl*72 + nq] = packh8(h);
  *(uint4*)&T[kl*72 + nq + 8] = packh8(h+8);
  __syncthreads();
  int nl = tid>>2, kq = (tid&3)*16;
  int n = n0 + nl;
  if (n < 34004){
    u16 o[16];
    #pragma unroll
    for(int j=0;j<16;++j) o[j] = T[(kq+j)*72 + nl];
    *(uint4*)&WfT[(size_t)n*512 + k0 + kq]     = packh8(o);
    *(uint4*)&WfT[(size_t)n*512 + k0 + kq + 8] = packh8(o+8);
  }
}

// ---------- generic 128x128 bf16 MFMA GEMM:  C[M,N] = A[M,K] * Bt[N,K]^T ----------
template<int EPI>
__global__ __launch_bounds__(256,2) void gemm_bf16(
    const u16* __restrict__ A, const u16* __restrict__ Bt,
    int M, int N, int K,
    float* __restrict__ Cf, u16* __restrict__ Cb,
    const float* __restrict__ bias, float* __restrict__ Cout){
  __shared__ u16 LSbuf[2*128*40];
  u16* Als = LSbuf;
  u16* Bls = LSbuf + 128*40;
  int tid = threadIdx.x;
  int c0 = blockIdx.x*128, r0 = blockIdx.y*128;
  int wid = tid>>6, wr = wid>>1, wc = wid&1;
  int l15 = tid&15, l4 = (tid>>4)&3;
  f4v acc[4][4];
  #pragma unroll
  for(int m=0;m<4;++m)
  #pragma unroll
  for(int n=0;n<4;++n)
  #pragma unroll
  for(int i=0;i<4;++i) acc[m][n][i] = 0.f;

  int r = tid>>1, hf = tid&1;
  size_t arow = (size_t)min(r0 + r, M-1);
  size_t brow = (size_t)min(c0 + r, N-1);
  const u16* abase = A  + arow*K + hf*16;
  const u16* bbase = Bt + brow*K + hf*16;
  int nk = K >> 5;
  uint4 a0 = ((const uint4*)abase)[0], a1 = ((const uint4*)abase)[1];
  uint4 b0 = ((const uint4*)bbase)[0], b1 = ((const uint4*)bbase)[1];
  for (int ch=0; ch<nk; ++ch){
    __syncthreads();
    *(uint4*)&Als[r*40 + hf*16]     = a0;
    *(uint4*)&Als[r*40 + hf*16 + 8] = a1;
    *(uint4*)&Bls[r*40 + hf*16]     = b0;
    *(uint4*)&Bls[r*40 + hf*16 + 8] = b1;
    __syncthreads();
    if (ch+1 < nk){
      const uint4* ap = (const uint4*)(abase + (ch+1)*32);
      const uint4* bp = (const uint4*)(bbase + (ch+1)*32);
      a0 = ap[0]; a1 = ap[1]; b0 = bp[0]; b1 = bp[1];
    }
    s8v af[4], bfr[4];
    #pragma unroll
    for(int m=0;m<4;++m) af[m]  = *(const s8v*)&Als[(wr*64 + m*16 + l15)*40 + l4*8];
    #pragma unroll
    for(int n=0;n<4;++n) bfr[n] = *(const s8v*)&Bls[(wc*64 + n*16 + l15)*40 + l4*8];
    #pragma unroll
    for(int m=0;m<4;++m)
    #pragma unroll
    for(int n=0;n<4;++n)
      acc[m][n] = __builtin_amdgcn_mfma_f32_16x16x32_bf16(af[m], bfr[n], acc[m][n], 0,0,0);
  }
  // epilogue: LDS-staged transpose to full-line float4 stores
  __syncthreads();
  float* eps = ((float*)LSbuf) + wid*1024;   // 16 rows x 64 cols per wave
  #pragma unroll
  for(int m=0;m<4;++m){
    #pragma unroll
    for(int n=0;n<4;++n)
    #pragma unroll
    for(int i=0;i<4;++i)
      eps[(l4*4 + i)*64 + n*16 + l15] = acc[m][n][i];
    #pragma unroll
    for(int q=0;q<4;++q){
      int row = l4 + q*4;
      f4v v = *(const f4v*)&eps[row*64 + l15*4];
      int gr = r0 + wr*64 + m*16 + row;
      int gc = c0 + wc*64 + l15*4;
      if (gr < M && gc < N){
        if constexpr (EPI==0){
          *(f4v*)&Cf[(size_t)gr*N + gc] = v;
        } else if constexpr (EPI==1){
          f4v bv = *(const f4v*)&bias[gc];
          v += bv;
          *(f4v*)&Cf[(size_t)gr*N + gc] = v;
        } else if constexpr (EPI==2){
          unsigned p0 = ((unsigned)f2bf(v[1])<<16) | f2bf(v[0]);
          unsigned p1 = ((unsigned)f2bf(v[3])<<16) | f2bf(v[2]);
          uint2 pk; pk.x = p0; pk.y = p1;
          *(uint2*)&Cb[(size_t)gr*N + gc] = pk;
        } else {
          f4v bv = *(const f4v*)&bias[gc];
          v += bv;
          int b_ = gr&63, tt = gr>>6;
          *(f4v*)&Cout[((size_t)(b_*59 + tt))*34004 + gc] = v;
        }
      }
    }
  }
}

// ---------- persistent recurrence kernel (fence-free, LDS-staged A) ----------
// 72 blocks x 256 threads (9 k-slices x 8 col-groups of 256 pc), plain launch.
// Phase A: block stages its 64KB A-slice (hhi/hlo, coherent loads) into LDS once;
// each of 4 waves computes a 64b x 64pc x 512k tile (A from LDS, B cached normal).
// zparts stored in natural pc order -> 64B-coalesced coherent stores.
// Phase B (blocks 0..63): coalesced coherent zparts gather + LDS slot-scatter,
// then LSTM + q + scores/softmax + ctx as before.
// Monotonic relaxed barriers; vmcnt-drain before arrivals.
#define NBLK 72

DI void arrive(unsigned* cnt, unsigned* root, unsigned subtgt){
  unsigned a = __hip_atomic_fetch_add(cnt, 1u, __ATOMIC_RELAXED, __HIP_MEMORY_SCOPE_AGENT);
  if (a == subtgt - 1u)
    __hip_atomic_fetch_add(root, 1u, __ATOMIC_RELAXED, __HIP_MEMORY_SCOPE_AGENT);
}
DI void spinge(unsigned* p, unsigned tgt){
  while (__hip_atomic_load(p, __ATOMIC_RELAXED, __HIP_MEMORY_SCOPE_AGENT) < tgt)
    __builtin_amdgcn_s_sleep(1);
}

__global__ __launch_bounds__(256,2) void persist(
    const u16* __restrict__ wzT, const u16* __restrict__ buhT,
    u16* __restrict__ hhi, u16* __restrict__ hlo,
    float* __restrict__ zparts, const float* __restrict__ Zemb,
    float* __restrict__ cst, float* __restrict__ h2X, float* __restrict__ ctxX,
    const u16* __restrict__ wqB, const float* __restrict__ keys,
    const float* __restrict__ enc, const float* __restrict__ vv,
    unsigned* bar){
  __shared__ float smem[16832];       // 67,328 B: phase A Als[64][520] u16; phase B scratch
  u16* Als = (u16*)smem;
  unsigned* barAc = bar;              // + (bid&7)*64, 9 arrivals per line
  unsigned* barAr = bar + 512;
  unsigned* barBc = bar + 576;        // + (bid&7)*64, 8 arrivals per line
  unsigned* barBr = bar + 1088;
  int bid = blockIdx.x, tid = threadIdx.x;
  int wv = tid>>6, lane = tid&63;
  int l15 = lane&15, l4 = lane>>4;
  int sl = bid>>3, cg = bid&7;
  int pc0 = cg*256 + wv*64;

  for (int t=0; t<59; ++t){
    int variant = (t==0) ? 0 : 1;
    int nsl = (t==0) ? 3 : 9;
    // ---- phase A: z-GEMM ----
    if (sl < nsl){
      const u16* src; int innerB, kB0; const u16* Bt; int physK;
      if (variant==0){
        src = (sl==1) ? hlo : hhi; innerB = 0;
        kB0 = (sl==2) ? 512 : 0;
        Bt = buhT; physK = 1024;
      } else {
        int sg = sl/3;
        src = (sg==1) ? hlo : hhi; innerB = (sl%3)*512;
        kB0 = (sg==2) ? (1536 + (sl%3)*512) : ((sl%3)*512);
        Bt = wzT; physK = 3072;
      }
      // stage A-slice: 64 rows x 512 k -> LDS [64][520] (coherent loads, once/step)
      {
        int k8 = lane*8;
        #pragma unroll
        for (int it=0; it<16; ++it){
          int row = wv + it*4;
          uint4 v = cohld128(src + (size_t)row*1536 + innerB + k8);
          *(uint4*)&Als[row*520 + k8] = v;
        }
      }
      __syncthreads();
      // GEMM: wave computes 64 b x 64 pc over full 512 k (A from LDS, B cached)
      f4v acc[4][4];
      #pragma unroll
      for(int m=0;m<4;++m)
      #pragma unroll
      for(int n=0;n<4;++n)
      #pragma unroll
      for(int i=0;i<4;++i) acc[m][n][i] = 0.f;

      uint4 Bb0[4], Bb1[4];
      auto loadB = [&](uint4* bb, int ch){
        int kk = kB0 + ch*32 + l4*8;
        #pragma unroll
        for(int n=0;n<4;++n)
          bb[n] = *(const uint4*)(Bt + (size_t)(pc0 + n*16 + l15)*physK + kk);
      };
      auto mmac = [&](const uint4* bb, int ch){
        s8v af[4];
        #pragma unroll
        for(int m=0;m<4;++m)
          af[m] = *(const s8v*)&Als[(m*16 + l15)*520 + ch*32 + l4*8];
        #pragma unroll
        for(int m=0;m<4;++m)
        #pragma unroll
        for(int n=0;n<4;++n)
          acc[m][n] = __builtin_amdgcn_mfma_f32_16x16x32_bf16(af[m], u4s8(bb[n]), acc[m][n], 0,0,0);
      };
      loadB(Bb0, 0); loadB(Bb1, 1);
      #pragma unroll 1
      for (int ch=0; ch<16; ch+=2){
        mmac(Bb0, ch);   if (ch+2 < 16) loadB(Bb0, ch+2);
        mmac(Bb1, ch+1); if (ch+3 < 16) loadB(Bb1, ch+3);
      }
      // epilogue: natural pc order, 16-lane 64B-coalesced coherent stores
      float* zp = zparts + (size_t)sl*131072;
      #pragma unroll
      for(int m=0;m<4;++m)
      #pragma unroll
      for(int n=0;n<4;++n)
      #pragma unroll
      for(int i=0;i<4;++i){
        int b = m*16 + l4*4 + i;
        int pc = pc0 + n*16 + l15;
        cohst32(&zp[(size_t)b*2048 + pc], __float_as_uint(acc[m][n][i]));
      }
    }
    asm volatile("s_waitcnt vmcnt(0)" ::: "memory");
    __syncthreads();
    if (tid==0) arrive(barAc + (bid&7)*64, barAr, 9u*(unsigned)(t+1));

    // ---- phase B: LSTM + attention (blocks 0..63) ----
    if (bid < 64){
      if (tid==0) spinge(barAr, 8u*(unsigned)(t+1));
      __syncthreads();
      asm volatile("" ::: "memory");
      int b = bid;
      float* zl  = smem;            // 2048
      float* h2s = smem + 2048;     // 512
      float* vs2 = smem + 2560;     // 512
      float* qs  = smem + 3072;     // 512
      float* qpl = smem + 3584;     // 4096
      float* scl = smem + 7680;     // 32
      float* alw = smem + 7712;     // 32
      // z-sum gather (coalesced coherent) + LDS slot-scatter
      {
        int p8 = tid*8;
        f4v z0; z0[0]=0.f; z0[1]=0.f; z0[2]=0.f; z0[3]=0.f;
        f4v z1 = z0;
        for(int s2=0; s2<nsl; ++s2){
          const float* zp = &zparts[(size_t)s2*131072 + (size_t)b*2048 + p8];
          z0 += cohldf4(zp);
          z1 += cohldf4(zp+4);
        }
        #pragma unroll
        for(int e=0;e<4;++e){
          zl[pc2slot(p8+e)]   = z0[e];
          zl[pc2slot(p8+4+e)] = z1[e];
        }
      }
      __syncthreads();
      // LSTM: units j0=2*tid, j0+1 (slot-contiguous f4v reads from zl + Zemb)
      {
        int j0 = tid*2;
        int base = (j0>>3)*32 + (j0&7)*4;
        const float* ze = &Zemb[(size_t)t*131072 + (size_t)b*2048 + base];
        f4v s40 = *(const f4v*)ze       + *(const f4v*)&zl[base];
        f4v s41 = *(const f4v*)(ze+4)   + *(const f4v*)&zl[base+4];
        float2 cp = *(const float2*)&cst[(size_t)b*512 + j0];
        float c20 = sigm(s40[1])*cp.x + sigm(s40[0])*tanhx(s40[2]);
        float h20 = sigm(s40[3])*tanhx(c20);
        float c21 = sigm(s41[1])*cp.y + sigm(s41[0])*tanhx(s41[2]);
        float h21 = sigm(s41[3])*tanhx(c21);
        *(float2*)&cst[(size_t)b*512 + j0] = make_float2(c20,c21);
        *(float2*)&h2X[(size_t)(t+1)*32768 + (size_t)b*512 + j0] = make_float2(h20,h21);
        h2s[j0]=h20; h2s[j0+1]=h21; vs2[j0]=vv[j0]; vs2[j0+1]=vv[j0+1];
        u16 a0=f2bf(h20), a1=f2bf(h21);
        cohst32(&hhi[(size_t)b*1536 + j0], (unsigned)a0 | ((unsigned)a1<<16));
        u16 b0=f2bf(h20-bf2f(a0)), b1=f2bf(h21-bf2f(a1));
        cohst32(&hlo[(size_t)b*1536 + j0], (unsigned)b0 | ((unsigned)b1<<16));
      }
      __syncthreads();
      // q = h2 @ Wq : 8 h-slices x 32 threads x 16 cols
      {
        int hs = tid>>5, c16 = (tid&31)*16;
        float qp[16];
        #pragma unroll
        for(int j=0;j<16;++j) qp[j] = 0.f;
        for(int hh=0; hh<64; ++hh){
          int h = hs*64 + hh;
          float hv = h2s[h];
          float w0[8], w1[8];
          unp8(*(const uint4*)(wqB + (size_t)h*512 + c16), w0);
          unp8(*(const uint4*)(wqB + (size_t)h*512 + c16 + 8), w1);
          #pragma unroll
          for(int j=0;j<8;++j){ qp[j] += hv*w0[j]; qp[8+j] += hv*w1[j]; }
        }
        #pragma unroll
        for(int j=0;j<16;j+=4)
          *(f4v*)&qpl[hs*512 + c16 + j] = *(const f4v*)&qp[j];
      }
      __syncthreads();
      #pragma unroll
      for(int u=0;u<2;++u){
        int c = tid + u*256;
        float s = 0.f;
        #pragma unroll
        for(int hs=0;hs<8;++hs) s += qpl[hs*512 + c];
        qs[c] = s;
      }
      __syncthreads();
      // scores: 8 threads per s (32 s), 64 h each
      {
        int s = tid>>3, hh = tid&7;
        const float* kb = keys + ((size_t)(b*32 + s))*512 + hh*64;
        const float* qq = qs + hh*64;
        const float* vw = vs2 + hh*64;
        float part = 0.f;
        #pragma unroll 4
        for(int i4=0;i4<16;++i4){
          float4 kv = *(const float4*)&kb[i4*4];
          int h = i4*4;
          part += vw[h+0]*tanhx(kv.x + qq[h+0]);
          part += vw[h+1]*tanhx(kv.y + qq[h+1]);
          part += vw[h+2]*tanhx(kv.z + qq[h+2]);
          part += vw[h+3]*tanhx(kv.w + qq[h+3]);
        }
        #pragma unroll
        for(int m=1;m<8;m<<=1) part += __shfl_xor(part, m, 64);
        if (hh==0) scl[s] = part;
      }
      __syncthreads();
      // softmax over 32
      if (tid < 32){
        float sc = scl[tid];
        float mx = sc;
        #pragma unroll
        for(int m=1;m<32;m<<=1) mx = fmaxf(mx, __shfl_xor(mx, m, 64));
        float e = __expf(sc - mx);
        float sm = e;
        #pragma unroll
        for(int m=1;m<32;m<<=1) sm += __shfl_xor(sm, m, 64);
        alw[tid] = e/sm;
      }
      __syncthreads();
      // ctx: 4 cols per thread (float4 enc loads)
      {
        int cc = tid*4;
        const float* eb = enc + (size_t)b*32768;
        f4v c4; c4[0]=0.f; c4[1]=0.f; c4[2]=0.f; c4[3]=0.f;
        for(int s=0;s<32;++s){
          float al = alw[s];
          f4v e4 = *(const f4v*)&eb[(size_t)s*1024 + cc];
          c4 += e4 * al;
        }
        *(f4v*)&ctxX[(size_t)(t+1)*65536 + (size_t)b*1024 + cc] = c4;
        u16 x0=f2bf(c4[0]), x1=f2bf(c4[1]), x2=f2bf(c4[2]), x3=f2bf(c4[3]);
        u64 pk = (u64)x0 | ((u64)x1<<16) | ((u64)x2<<32) | ((u64)x3<<48);
        cohst64(&hhi[(size_t)b*1536 + 512 + cc], pk);
        u16 y0=f2bf(c4[0]-bf2f(x0)), y1=f2bf(c4[1]-bf2f(x1));
        u16 y2=f2bf(c4[2]-bf2f(x2)), y3=f2bf(c4[3]-bf2f(x3));
        u64 pl = (u64)y0 | ((u64)y1<<16) | ((u64)y2<<32) | ((u64)y3<<48);
        cohst64(&hlo[(size_t)b*1536 + 512 + cc], pl);
      }
      asm volatile("s_waitcnt vmcnt(0)" ::: "memory");
      __syncthreads();
      if (tid==0) arrive(barBc + (bid&7)*64, barBr, 8u*(unsigned)(t+1));
    }
    // end-of-step: everyone waits for phase B completion
    if (tid==0) spinge(barBr, 8u*(unsigned)(t+1));
    __syncthreads();
    asm volatile("" ::: "memory");
  }
}

// ---------- host ----------
extern "C" void kernel_launch(void* const* d_in, const int* in_sizes, int n_in,
                              void* d_out, int out_size, void* d_ws, size_t ws_size,
                              hipStream_t stream){
  const int*   dec = (const int*)d_in[0];
  const float* enc = (const float*)d_in[1];
  const float* eh  = (const float*)d_in[2];
  const float* ec  = (const float*)d_in[3];
  const float* emb = (const float*)d_in[4];
  const float* Wx  = (const float*)d_in[5];
  const float* Uh  = (const float*)d_in[6];
  const float* bb  = (const float*)d_in[7];
  const float* Wm  = (const float*)d_in[8];
  const float* Wq  = (const float*)d_in[9];
  const float* vv  = (const float*)d_in[10];
  const float* Wa  = (const float*)d_in[11];
  const float* Wf  = (const float*)d_in[12];
  const float* bf  = (const float*)d_in[13];
  float* out = (float*)d_out;

  // ---- workspace carving ----
  char* w = (char*)d_ws; size_t off = 0;
  auto alloc = [&](size_t bytes)->char*{ char* p = w + off; off = (off + bytes + 255) & ~(size_t)255; return p; };
  u16* WfT   = (u16*)alloc((size_t)34004*512*2);
  u16* attn2 = (u16*)alloc((size_t)3776*512*2);
  size_t liveEnd = off;
  const size_t needB = (size_t)130<<20;
  bool fits = (ws_size >= liveEnd + needB);
  char* wb = fits ? (w + liveEnd) : (char*)d_out;
  size_t offb = 0;
  auto allocB = [&](size_t bytes)->char*{ char* p = wb + offb; offb = (offb + bytes + 255) & ~(size_t)255; return p; };

  u16* wzT   = (u16*)allocB((size_t)2048*3072*2);
  u16* buhT  = (u16*)allocB((size_t)2048*1024*2);
  u16* wqB   = (u16*)allocB((size_t)512*512*2);
  u16* waT   = (u16*)allocB((size_t)512*1536*2);
  u16* wmT   = (u16*)allocB((size_t)512*1024*2);
  u16* wxtpT = (u16*)allocB((size_t)2048*320*2);
  u16* wxaT  = (u16*)allocB((size_t)2048*1536*2);
  u16* waA   = (u16*)allocB((size_t)1536*1536*2);
  float* wzc = (float*)allocB((size_t)2048*1536*4);
  u16* embB  = (u16*)allocB((size_t)3776*320*2);
  u16* encB  = (u16*)allocB((size_t)2048*1024*2);
  float* Zemb  = (float*)allocB((size_t)3776*2048*4);
  float* keys  = (float*)allocB((size_t)2048*512*4);
  float* zparts= (float*)allocB((size_t)9*64*2048*4);
  float* h2X   = (float*)allocB((size_t)60*64*512*4);
  float* ctxX  = (float*)allocB((size_t)60*64*1024*4);
  float* cst   = (float*)allocB((size_t)64*512*4);
  float* bp    = (float*)allocB((size_t)2048*4);
  u16* A2c   = (u16*)allocB((size_t)3776*1536*2);
  u16* hhi   = (u16*)allocB((size_t)64*1536*2);
  u16* hlo   = (u16*)allocB((size_t)64*1536*2);
  unsigned* bar = (unsigned*)allocB(8192);

  // ---- precompute ----
  k_init<<<526,256,0,stream>>>(bb, eh, ec, bp, h2X, cst, ctxX, bar);
  k_hinit<<<384,256,0,stream>>>(eh, hhi, hlo);
  k_embgather<<<(3776*40+255)/256,256,0,stream>>>(dec, emb, embB);
  k_cvt<<<(262144+255)/256,256,0,stream>>>(enc, encB, 262144);
  k_cvt<<<(32768+255)/256,256,0,stream>>>(Wq, wqB, 32768);
  k_wmT<<<(512*128+255)/256,256,0,stream>>>(Wm, wmT);
  k_waT<<<(512*192+255)/256,256,0,stream>>>(Wa, waT);
  k_wxtpT<<<(2048*40+255)/256,256,0,stream>>>(Wx, wxtpT);
  k_wxaT<<<(2048*192+255)/256,256,0,stream>>>(Wx, wxaT);
  k_buhT<<<(2048*128+255)/256,256,0,stream>>>(Uh, buhT);
  k_waA<<<(1536*192+255)/256,256,0,stream>>>(Wa, waA);
  k_wfT<<<dim3(532,8),256,0,stream>>>(Wf, WfT);

  // Zemb = gather(emb) @ Wx_top (slot cols) + b   [3776][2048]
  gemm_bf16<1><<<dim3(16,30),256,0,stream>>>(embB, wxtpT, 3776, 2048, 320, Zemb, nullptr, bp, nullptr);
  // keys = enc @ Wm  [2048][512]
  gemm_bf16<0><<<dim3(4,16),256,0,stream>>>(encB, wmT, 2048, 512, 1024, keys, nullptr, nullptr, nullptr);
  // WzcT = Wx_att^T @ Wa^T (transposed composite, split-precision)  [2048 pc][1536 r]
  gemm_bf16<0><<<dim3(12,16),256,0,stream>>>(wxaT, waA, 2048, 1536, 1536, wzc, nullptr, nullptr, nullptr);
  // W'z^T = split( WzcT + Uh(top) )^T   [2048][3072]
  k_wzcT<<<(2048*384+255)/256,256,0,stream>>>(wzc, Uh, wzT);

  // ---- recurrence: one persistent kernel (plain launch + fence-free barriers) ----
  persist<<<NBLK,256,0,stream>>>(wzT, buhT, hhi, hlo, zparts, Zemb, cst, h2X, ctxX,
                                 wqB, keys, enc, vv, bar);

  // ---- deferred attn2 + logits ----
  k_a2dump<<<(3776*192+255)/256,256,0,stream>>>(h2X, ctxX, A2c);
  gemm_bf16<2><<<dim3(4,30),256,0,stream>>>(A2c, waT, 3776, 512, 1536, nullptr, attn2, nullptr, nullptr);
  gemm_bf16<3><<<dim3(266,30),256,0,stream>>>(attn2, WfT, 3776, 34004, 512, nullptr, nullptr, bf, out);
}

// Round 7
// 2848.986 us; speedup vs baseline: 1.6816x; 1.6816x over previous
//
#include <hip/hip_runtime.h>
#include <hip/hip_bf16.h>
#include <cstdint>
#include <cstddef>

typedef unsigned short u16;
typedef unsigned long long u64;
typedef short s8v __attribute__((ext_vector_type(8)));
typedef float f4v __attribute__((ext_vector_type(4)));

#define DI __device__ __forceinline__

// ---------- helpers ----------
DI u16 f2bf(float f){ unsigned u = __float_as_uint(f); u += 0x7fffu + ((u>>16)&1u); return (u16)(u>>16); }
DI float bf2f(u16 h){ return __uint_as_float(((unsigned)h)<<16); }
DI int ocol(int pc){ return ((pc>>3)&3)*512 + (pc>>5)*8 + (pc&7); }  // packed col -> original col
// slot layout (gate-contiguous): slot s = hb*32 + jj*4 + g  ->  original col
DI int ocol2(int s){ int pc = (s & ~31) | ((s&3)<<3) | ((s>>2)&7); return ocol(pc); }
DI int pc2slot(int pc){ return (pc & ~31) | ((pc&7)<<2) | ((pc>>3)&3); }
DI float sigm(float x){ x = fminf(fmaxf(x,-30.f),30.f); return 1.f/(1.f+__expf(-x)); }
DI float tanhx(float x){ x = fminf(fmaxf(x,-15.f),15.f); float e = __expf(-2.f*x); return (1.f-e)/(1.f+e); }
DI uint4 packh8(const u16* h){
  uint4 r; r.x=(unsigned)h[0]|((unsigned)h[1]<<16); r.y=(unsigned)h[2]|((unsigned)h[3]<<16);
  r.z=(unsigned)h[4]|((unsigned)h[5]<<16); r.w=(unsigned)h[6]|((unsigned)h[7]<<16); return r;
}
DI void unp8(uint4 w, float* o){
  o[0]=bf2f((u16)(w.x&0xffffu)); o[1]=bf2f((u16)(w.x>>16));
  o[2]=bf2f((u16)(w.y&0xffffu)); o[3]=bf2f((u16)(w.y>>16));
  o[4]=bf2f((u16)(w.z&0xffffu)); o[5]=bf2f((u16)(w.z>>16));
  o[6]=bf2f((u16)(w.w&0xffffu)); o[7]=bf2f((u16)(w.w>>16));
}
DI s8v u4s8(uint4 u){ union{uint4 a; s8v b;} t; t.a=u; return t.b; }

// ---------- agent-coherent (fence-free) access helpers ----------
DI unsigned cohld32(const void* p){
  return __hip_atomic_load((const unsigned*)p, __ATOMIC_RELAXED, __HIP_MEMORY_SCOPE_AGENT);
}
DI u64 cohld64(const void* p){
  return __hip_atomic_load((const u64*)p, __ATOMIC_RELAXED, __HIP_MEMORY_SCOPE_AGENT);
}
DI f4v cohldf4(const float* p){
  u64 lo = cohld64(p);
  u64 hi = cohld64(p + 2);
  f4v r;
  r[0]=__uint_as_float((unsigned)lo); r[1]=__uint_as_float((unsigned)(lo>>32));
  r[2]=__uint_as_float((unsigned)hi); r[3]=__uint_as_float((unsigned)(hi>>32));
  return r;
}
DI void cohst32(void* p, unsigned v){
  __hip_atomic_store((unsigned*)p, v, __ATOMIC_RELAXED, __HIP_MEMORY_SCOPE_AGENT);
}
DI void cohst64(void* p, u64 v){
  __hip_atomic_store((u64*)p, v, __ATOMIC_RELAXED, __HIP_MEMORY_SCOPE_AGENT);
}

// ---------- small builder kernels ----------
__global__ void k_init(const float* bb, const float* eh, const float* ec,
                       float* bp, float* h2X, float* cst, float* ctxX, unsigned* flags){
  int i = blockIdx.x*256 + threadIdx.x;
  if (i < 2048) bp[i] = bb[ocol2(i)];
  else if (i < 2048+32768) h2X[i-2048] = eh[i-2048];
  else if (i < 2048+65536) cst[i-34816] = ec[i-34816];
  else if (i < 2048+131072) ctxX[i-67584] = 0.f;
  else if (i < 2048+131072+30208) flags[i-133120] = 0u;
}

// hcat = [h0 | zeros] as bf16 hi/lo split, rows b, 1536 cols
__global__ void k_hinit(const float* __restrict__ eh, u16* __restrict__ hhi, u16* __restrict__ hlo){
  int i = blockIdx.x*256 + threadIdx.x; if (i >= 64*1536) return;
  int c = i % 1536;
  float f = (c < 512) ? eh[(i/1536)*512 + c] : 0.f;
  u16 hi = f2bf(f);
  hhi[i] = hi;
  hlo[i] = (c < 512) ? f2bf(f - bf2f(hi)) : (u16)0;
}

__global__ void k_cvt(const float* __restrict__ src, u16* __restrict__ dst, int octs){
  int g = blockIdx.x*256 + threadIdx.x; if (g >= octs) return;
  const float4* p = (const float4*)(src + (size_t)g*8);
  float4 a = p[0], b = p[1];
  u16 h[8] = {f2bf(a.x),f2bf(a.y),f2bf(a.z),f2bf(a.w),f2bf(b.x),f2bf(b.y),f2bf(b.z),f2bf(b.w)};
  *(uint4*)&dst[(size_t)g*8] = packh8(h);
}

__global__ void k_embgather(const int* __restrict__ dec, const float* __restrict__ emb, u16* __restrict__ dst){
  int g = blockIdx.x*256 + threadIdx.x; if (g >= 3776*40) return;
  int row = g/40, o = g%40;
  int b = row & 63, t = row >> 6;
  int tok = dec[b*59 + t];
  u16 h[8];
  #pragma unroll
  for(int j=0;j<8;++j){ int k = o*8+j; float f = (k<300)? emb[(size_t)tok*300 + k] : 0.f; h[j]=f2bf(f); }
  *(uint4*)&dst[(size_t)row*320 + o*8] = packh8(h);
}

__global__ void k_wmT(const float* __restrict__ Wm, u16* __restrict__ dst){
  int g = blockIdx.x*256 + threadIdx.x; if (g >= 512*128) return;
  int hcol = g/128, o = g%128;
  u16 h[8];
  #pragma unroll
  for(int j=0;j<8;++j){ int m = o*8+j; h[j]=f2bf(Wm[(size_t)m*512 + hcol]); }
  *(uint4*)&dst[(size_t)hcol*1024 + o*8] = packh8(h);
}

__global__ void k_waT(const float* __restrict__ Wa, u16* __restrict__ dst){
  int g = blockIdx.x*256 + threadIdx.x; if (g >= 512*192) return;
  int c = g/192, o = g%192;
  u16 h[8];
  #pragma unroll
  for(int j=0;j<8;++j){ int k = o*8+j; h[j]=f2bf(Wa[(size_t)k*512 + c]); }
  *(uint4*)&dst[(size_t)c*1536 + o*8] = packh8(h);
}

// Wx top rows (emb part), cols in slot (gate-contiguous) order -> Zemb lands gate-contiguous
__global__ void k_wxtpT(const float* __restrict__ Wx, u16* __restrict__ dst){
  int g = blockIdx.x*256 + threadIdx.x; if (g >= 2048*40) return;
  int pc = g/40, o = g%40; int oc = ocol2(pc);
  u16 h[8];
  #pragma unroll
  for(int j=0;j<8;++j){ int e = o*8+j; float f = (e<300)? Wx[(size_t)e*2048 + oc] : 0.f; h[j]=f2bf(f); }
  *(uint4*)&dst[(size_t)pc*320 + o*8] = packh8(h);
}

// Wx_att^T splits: segs [hi(512) | hi(512) | lo(512)] along k'  (packed-pc cols)
__global__ void k_wxaT(const float* __restrict__ Wx, u16* __restrict__ dst){
  int g = blockIdx.x*256 + threadIdx.x; if (g >= 2048*192) return;
  int pc = g/192, o = g%192; int oc = ocol(pc);
  u16 h[8];
  #pragma unroll
  for(int j=0;j<8;++j){
    int kp = o*8+j; int seg = kp>>9; int jd = kp&511;
    float f = Wx[(size_t)(300+jd)*2048 + oc];
    u16 hi = f2bf(f);
    h[j] = (seg==2) ? f2bf(f - bf2f(hi)) : hi;
  }
  *(uint4*)&dst[(size_t)pc*1536 + o*8] = packh8(h);
}

// Wa splits (A side of composite GEMM): segs [hi | lo | hi]
__global__ void k_waA(const float* __restrict__ Wa, u16* __restrict__ dst){
  int g = blockIdx.x*256 + threadIdx.x; if (g >= 1536*192) return;
  int r = g/192, o = g%192;
  u16 h[8];
  #pragma unroll
  for(int j=0;j<8;++j){
    int kp = o*8+j; int seg = kp>>9; int jd = kp&511;
    float f = Wa[(size_t)r*512 + jd];
    u16 hi = f2bf(f);
    h[j] = (seg==1) ? f2bf(f - bf2f(hi)) : hi;
  }
  *(uint4*)&dst[(size_t)r*1536 + o*8] = packh8(h);
}

// Uh^T packed splits: phys [hi(512) | lo(512)]
__global__ void k_buhT(const float* __restrict__ Uh, u16* __restrict__ dst){
  int g = blockIdx.x*256 + threadIdx.x; if (g >= 2048*128) return;
  int pc = g/128, o = g%128; int oc = ocol(pc);
  u16 h[8];
  #pragma unroll
  for(int j=0;j<8;++j){
    int kp = o*8+j; int r = kp&511;
    float f = Uh[(size_t)r*2048 + oc];
    u16 hi = f2bf(f);
    h[j] = (kp<512) ? hi : f2bf(f - bf2f(hi));
  }
  *(uint4*)&dst[(size_t)pc*1024 + o*8] = packh8(h);
}

// (WzcT + Uh-on-top)^T splits: phys [hi(1536) | lo(1536)]
// wzcT is [2048 pc][1536 r]  (transposed composite) -> row-coalesced reads
__global__ void k_wzcT(const float* __restrict__ wzcT, const float* __restrict__ Uh, u16* __restrict__ dst){
  int g = blockIdx.x*256 + threadIdx.x; if (g >= 2048*384) return;
  int pc = g/384, o = g%384; int oc = ocol(pc);
  u16 h[8];
  #pragma unroll
  for(int j=0;j<8;++j){
    int kp = o*8+j; int r = kp % 1536;
    float f = wzcT[(size_t)pc*1536 + r] + ((r<512) ? Uh[(size_t)r*2048 + oc] : 0.f);
    u16 hi = f2bf(f);
    h[j] = (kp<1536) ? hi : f2bf(f - bf2f(hi));
  }
  *(uint4*)&dst[(size_t)pc*3072 + o*8] = packh8(h);
}

// A2cat = [h2 | ctx] bf16, rows r = t*64+b  (reads slot t+1 == row r+64)
__global__ void k_a2dump(const float* __restrict__ h2X, const float* __restrict__ ctxX, u16* __restrict__ dst){
  int g = blockIdx.x*256 + threadIdx.x; if (g >= 3776*192) return;
  int r = g/192, o = g%192;
  u16 h[8];
  #pragma unroll
  for(int j=0;j<8;++j){
    int k = o*8+j;
    float f = (k<512) ? h2X[(size_t)(r+64)*512 + k] : ctxX[(size_t)(r+64)*1024 + (k-512)];
    h[j] = f2bf(f);
  }
  *(uint4*)&dst[(size_t)r*1536 + o*8] = packh8(h);
}

// Wf [512][34004] f32 -> WfT [34004][512] bf16 (LDS-tiled transpose)
__global__ __launch_bounds__(256) void k_wfT(const float* __restrict__ Wf, u16* __restrict__ WfT){
  __shared__ u16 T[64*72];
  int n0 = blockIdx.x*64, k0 = blockIdx.y*64;
  int tid = threadIdx.x;
  int kl = tid>>2, nq = (tid&3)*16;
  u16 h[16];
  if (n0 + 64 <= 34004){
    const float4* p = (const float4*)(Wf + (size_t)(k0+kl)*34004 + n0 + nq);
    #pragma unroll
    for(int q=0;q<4;++q){ float4 f = p[q]; h[q*4+0]=f2bf(f.x); h[q*4+1]=f2bf(f.y); h[q*4+2]=f2bf(f.z); h[q*4+3]=f2bf(f.w); }
  } else {
    #pragma unroll
    for(int j=0;j<16;++j){ int n = n0+nq+j; float f = (n<34004)? Wf[(size_t)(k0+kl)*34004 + n] : 0.f; h[j]=f2bf(f); }
  }
  *(uint4*)&T[kl*72 + nq] = packh8(h);
  *(uint4*)&T[kl*72 + nq + 8] = packh8(h+8);
  __syncthreads();
  int nl = tid>>2, kq = (tid&3)*16;
  int n = n0 + nl;
  if (n < 34004){
    u16 o[16];
    #pragma unroll
    for(int j=0;j<16;++j) o[j] = T[(kq+j)*72 + nl];
    *(uint4*)&WfT[(size_t)n*512 + k0 + kq]     = packh8(o);
    *(uint4*)&WfT[(size_t)n*512 + k0 + kq + 8] = packh8(o+8);
  }
}

// ---------- generic 128x128 bf16 MFMA GEMM:  C[M,N] = A[M,K] * Bt[N,K]^T ----------
template<int EPI>
__global__ __launch_bounds__(256,2) void gemm_bf16(
    const u16* __restrict__ A, const u16* __restrict__ Bt,
    int M, int N, int K,
    float* __restrict__ Cf, u16* __restrict__ Cb,
    const float* __restrict__ bias, float* __restrict__ Cout){
  __shared__ u16 LSbuf[2*128*40];
  u16* Als = LSbuf;
  u16* Bls = LSbuf + 128*40;
  int tid = threadIdx.x;
  int c0 = blockIdx.x*128, r0 = blockIdx.y*128;
  int wid = tid>>6, wr = wid>>1, wc = wid&1;
  int l15 = tid&15, l4 = (tid>>4)&3;
  f4v acc[4][4];
  #pragma unroll
  for(int m=0;m<4;++m)
  #pragma unroll
  for(int n=0;n<4;++n)
  #pragma unroll
  for(int i=0;i<4;++i) acc[m][n][i] = 0.f;

  int r = tid>>1, hf = tid&1;
  size_t arow = (size_t)min(r0 + r, M-1);
  size_t brow = (size_t)min(c0 + r, N-1);
  const u16* abase = A  + arow*K + hf*16;
  const u16* bbase = Bt + brow*K + hf*16;
  int nk = K >> 5;
  uint4 a0 = ((const uint4*)abase)[0], a1 = ((const uint4*)abase)[1];
  uint4 b0 = ((const uint4*)bbase)[0], b1 = ((const uint4*)bbase)[1];
  for (int ch=0; ch<nk; ++ch){
    __syncthreads();
    *(uint4*)&Als[r*40 + hf*16]     = a0;
    *(uint4*)&Als[r*40 + hf*16 + 8] = a1;
    *(uint4*)&Bls[r*40 + hf*16]     = b0;
    *(uint4*)&Bls[r*40 + hf*16 + 8] = b1;
    __syncthreads();
    if (ch+1 < nk){
      const uint4* ap = (const uint4*)(abase + (ch+1)*32);
      const uint4* bp = (const uint4*)(bbase + (ch+1)*32);
      a0 = ap[0]; a1 = ap[1]; b0 = bp[0]; b1 = bp[1];
    }
    s8v af[4], bfr[4];
    #pragma unroll
    for(int m=0;m<4;++m) af[m]  = *(const s8v*)&Als[(wr*64 + m*16 + l15)*40 + l4*8];
    #pragma unroll
    for(int n=0;n<4;++n) bfr[n] = *(const s8v*)&Bls[(wc*64 + n*16 + l15)*40 + l4*8];
    #pragma unroll
    for(int m=0;m<4;++m)
    #pragma unroll
    for(int n=0;n<4;++n)
      acc[m][n] = __builtin_amdgcn_mfma_f32_16x16x32_bf16(af[m], bfr[n], acc[m][n], 0,0,0);
  }
  // epilogue: LDS-staged transpose to full-line float4 stores
  __syncthreads();
  float* eps = ((float*)LSbuf) + wid*1024;   // 16 rows x 64 cols per wave
  #pragma unroll
  for(int m=0;m<4;++m){
    #pragma unroll
    for(int n=0;n<4;++n)
    #pragma unroll
    for(int i=0;i<4;++i)
      eps[(l4*4 + i)*64 + n*16 + l15] = acc[m][n][i];
    #pragma unroll
    for(int q=0;q<4;++q){
      int row = l4 + q*4;
      f4v v = *(const f4v*)&eps[row*64 + l15*4];
      int gr = r0 + wr*64 + m*16 + row;
      int gc = c0 + wc*64 + l15*4;
      if (gr < M && gc < N){
        if constexpr (EPI==0){
          *(f4v*)&Cf[(size_t)gr*N + gc] = v;
        } else if constexpr (EPI==1){
          f4v bv = *(const f4v*)&bias[gc];
          v += bv;
          *(f4v*)&Cf[(size_t)gr*N + gc] = v;
        } else if constexpr (EPI==2){
          unsigned p0 = ((unsigned)f2bf(v[1])<<16) | f2bf(v[0]);
          unsigned p1 = ((unsigned)f2bf(v[3])<<16) | f2bf(v[2]);
          uint2 pk; pk.x = p0; pk.y = p1;
          *(uint2*)&Cb[(size_t)gr*N + gc] = pk;
        } else {
          f4v bv = *(const f4v*)&bias[gc];
          v += bv;
          int b_ = gr&63, tt = gr>>6;
          *(f4v*)&Cout[((size_t)(b_*59 + tt))*34004 + gc] = v;
        }
      }
    }
  }
}

// ---------- fused per-step kernel: z-GEMM + flag-sync + LSTM/attention ----------
// ONE launch per step, grid 512 = capacity-exact (2 blocks/CU x 256 CU) so all
// blocks are co-resident regardless of dispatch order (no deadlock).
// blocks 0..447: z-GEMM, 64 col-groups (32 pc) x 7 K-slices. A = hcat (hhi/hlo)
//   via NORMAL cached loads (fresh via launch boundary). B normal (L2-resident;
//   bid%8 == cg%8 keeps a col-group's slices on one XCD). zparts written with
//   relaxed agent stores (natural pc order); vmcnt drain; per-block done flag.
// blocks 448..511 (one per batch): poll all 448 flags (<=2 per thread), then
//   gather zparts with relaxed agent loads, LDS slot-scatter, LSTM + q + scores
//   + softmax + ctx; all state written with NORMAL stores for the next launch.
__global__ __launch_bounds__(256,2) void step_fused(
    int t,
    const u16* __restrict__ wzT, const u16* __restrict__ buhT,
    u16* __restrict__ hhi, u16* __restrict__ hlo,
    float* __restrict__ zparts, const float* __restrict__ Zemb,
    float* __restrict__ cst, float* __restrict__ h2X, float* __restrict__ ctxX,
    const u16* __restrict__ wqB, const float* __restrict__ keys,
    const float* __restrict__ enc, const float* __restrict__ vv,
    unsigned* __restrict__ flags){
  __shared__ float smem[8192];   // 32 KB
  int bid = blockIdx.x, tid = threadIdx.x;
  unsigned* flg = flags + (size_t)t*512;
  int variant = (t==0) ? 0 : 1;

  if (bid < 448){
    // ---- z-GEMM block ----
    int sl = bid/64, cg = bid%64;      // bid%8 == cg%8 -> slice locality per XCD
    int pc0 = cg*32;
    int wv = tid>>6, lane = tid&63;
    int l15 = lane&15, l4 = lane>>4;
    const u16* Bt = variant ? wzT : buhT;
    int physK = variant ? 3072 : 1024;
    int C = variant ? 144 : 48;        // total K-chunks (virtual K / 32)
    int ck0 = (sl*C)/7, ck1 = ((sl+1)*C)/7;

    f4v acc[4][2];
    #pragma unroll
    for(int m=0;m<4;++m)
    #pragma unroll
    for(int n=0;n<2;++n)
    #pragma unroll
    for(int i=0;i<4;++i) acc[m][n][i] = 0.f;

    for (int c = ck0 + wv; c < ck1; c += 4){
      int k1 = c*32;
      const u16* ap; int inner, kB;
      if (variant==0){
        inner = k1 & 511;
        ap = ((((k1>>9)&3)==1) ? hlo : hhi);
        kB = (k1 < 1024) ? (k1 & 511) : (k1 - 512);
      } else {
        int sg = k1/1536; inner = k1 - sg*1536;
        ap = (sg==1) ? hlo : hhi;
        kB = (k1 < 3072) ? (k1 % 1536) : (1536 + (k1 - 3072));
      }
      uint4 av[4], bv[2];
      #pragma unroll
      for(int m=0;m<4;++m)
        av[m] = *(const uint4*)(ap + (size_t)(m*16 + l15)*1536 + inner + l4*8);
      #pragma unroll
      for(int n=0;n<2;++n)
        bv[n] = *(const uint4*)(Bt + (size_t)(pc0 + n*16 + l15)*physK + kB + l4*8);
      #pragma unroll
      for(int m=0;m<4;++m){
        s8v am = u4s8(av[m]);
        #pragma unroll
        for(int n=0;n<2;++n)
          acc[m][n] = __builtin_amdgcn_mfma_f32_16x16x32_bf16(am, u4s8(bv[n]), acc[m][n], 0,0,0);
      }
    }
    // LDS reduce across the 4 K-interleaved waves
    float* red = smem + wv*2048;
    #pragma unroll
    for(int m=0;m<4;++m)
    #pragma unroll
    for(int n=0;n<2;++n)
    #pragma unroll
    for(int i=0;i<4;++i)
      red[(m*16 + l4*4 + i)*32 + n*16 + l15] = acc[m][n][i];
    __syncthreads();

    int rr = tid>>2, cq = (tid&3)*8;
    float* zp = zparts + (size_t)sl*131072 + (size_t)rr*2048 + pc0 + cq;
    #pragma unroll
    for(int k=0;k<2;++k){
      f4v s = *(const f4v*)&smem[0*2048 + rr*32 + cq + k*4];
      #pragma unroll
      for(int w=1;w<4;++w)
        s += *(const f4v*)&smem[w*2048 + rr*32 + cq + k*4];
      cohst64(&zp[k*4],     (u64)__float_as_uint(s[0]) | ((u64)__float_as_uint(s[1])<<32));
      cohst64(&zp[k*4 + 2], (u64)__float_as_uint(s[2]) | ((u64)__float_as_uint(s[3])<<32));
    }
    asm volatile("s_waitcnt vmcnt(0)" ::: "memory");
    __syncthreads();
    if (tid==0) cohst32(&flg[bid], 1u);

  } else {
    // ---- attention block (one per batch) ----
    int b = bid - 448;
    // wait for all 448 z-blocks (each thread watches <=2 flags)
    if (tid < 448){
      while (cohld32(&flg[tid]) == 0u) __builtin_amdgcn_s_sleep(1);
    }
    if (tid < 192){
      while (cohld32(&flg[tid+256]) == 0u) __builtin_amdgcn_s_sleep(1);
    }
    __syncthreads();
    asm volatile("" ::: "memory");

    float* zl  = smem;            // 2048
    float* h2s = smem + 2048;     // 512
    float* vs2 = smem + 2560;     // 512
    float* qs  = smem + 3072;     // 512
    float* qpl = smem + 3584;     // 4096
    float* scl = smem + 7680;     // 32
    float* alw = smem + 7712;     // 32
    // z-sum gather (coherent, batched) + LDS slot-scatter
    {
      int p8 = tid*8;
      f4v z0; z0[0]=0.f; z0[1]=0.f; z0[2]=0.f; z0[3]=0.f;
      f4v z1 = z0;
      for(int s2=0; s2<7; ++s2){
        const float* zp = &zparts[(size_t)s2*131072 + (size_t)b*2048 + p8];
        z0 += cohldf4(zp);
        z1 += cohldf4(zp+4);
      }
      #pragma unroll
      for(int e=0;e<4;++e){
        zl[pc2slot(p8+e)]   = z0[e];
        zl[pc2slot(p8+4+e)] = z1[e];
      }
    }
    __syncthreads();
    // LSTM: units j0=2*tid, j0+1  (normal stores; next launch sees them)
    {
      int j0 = tid*2;
      int base = (j0>>3)*32 + (j0&7)*4;
      const float* ze = &Zemb[(size_t)t*131072 + (size_t)b*2048 + base];
      f4v s40 = *(const f4v*)ze     + *(const f4v*)&zl[base];
      f4v s41 = *(const f4v*)(ze+4) + *(const f4v*)&zl[base+4];
      float2 cp = *(const float2*)&cst[(size_t)b*512 + j0];
      float c20 = sigm(s40[1])*cp.x + sigm(s40[0])*tanhx(s40[2]);
      float h20 = sigm(s40[3])*tanhx(c20);
      float c21 = sigm(s41[1])*cp.y + sigm(s41[0])*tanhx(s41[2]);
      float h21 = sigm(s41[3])*tanhx(c21);
      *(float2*)&cst[(size_t)b*512 + j0] = make_float2(c20,c21);
      *(float2*)&h2X[(size_t)(t+1)*32768 + (size_t)b*512 + j0] = make_float2(h20,h21);
      h2s[j0]=h20; h2s[j0+1]=h21; vs2[j0]=vv[j0]; vs2[j0+1]=vv[j0+1];
      u16 a0=f2bf(h20), a1=f2bf(h21);
      *(unsigned*)&hhi[(size_t)b*1536 + j0] = (unsigned)a0 | ((unsigned)a1<<16);
      u16 b0=f2bf(h20-bf2f(a0)), b1=f2bf(h21-bf2f(a1));
      *(unsigned*)&hlo[(size_t)b*1536 + j0] = (unsigned)b0 | ((unsigned)b1<<16);
    }
    __syncthreads();
    // q = h2 @ Wq : 8 h-slices x 32 threads x 16 cols
    {
      int hs = tid>>5, c16 = (tid&31)*16;
      float qp[16];
      #pragma unroll
      for(int j=0;j<16;++j) qp[j] = 0.f;
      for(int hh=0; hh<64; ++hh){
        int h = hs*64 + hh;
        float hv = h2s[h];
        float w0[8], w1[8];
        unp8(*(const uint4*)(wqB + (size_t)h*512 + c16), w0);
        unp8(*(const uint4*)(wqB + (size_t)h*512 + c16 + 8), w1);
        #pragma unroll
        for(int j=0;j<8;++j){ qp[j] += hv*w0[j]; qp[8+j] += hv*w1[j]; }
      }
      #pragma unroll
      for(int j=0;j<16;j+=4)
        *(f4v*)&qpl[hs*512 + c16 + j] = *(const f4v*)&qp[j];
    }
    __syncthreads();
    #pragma unroll
    for(int u=0;u<2;++u){
      int c = tid + u*256;
      float s = 0.f;
      #pragma unroll
      for(int hs=0;hs<8;++hs) s += qpl[hs*512 + c];
      qs[c] = s;
    }
    __syncthreads();
    // scores: 8 threads per s (32 s), 64 h each
    {
      int s = tid>>3, hh = tid&7;
      const float* kb = keys + ((size_t)(b*32 + s))*512 + hh*64;
      const float* qq = qs + hh*64;
      const float* vw = vs2 + hh*64;
      float part = 0.f;
      #pragma unroll 4
      for(int i4=0;i4<16;++i4){
        float4 kv = *(const float4*)&kb[i4*4];
        int h = i4*4;
        part += vw[h+0]*tanhx(kv.x + qq[h+0]);
        part += vw[h+1]*tanhx(kv.y + qq[h+1]);
        part += vw[h+2]*tanhx(kv.z + qq[h+2]);
        part += vw[h+3]*tanhx(kv.w + qq[h+3]);
      }
      #pragma unroll
      for(int m=1;m<8;m<<=1) part += __shfl_xor(part, m, 64);
      if (hh==0) scl[s] = part;
    }
    __syncthreads();
    // softmax over 32
    if (tid < 32){
      float sc = scl[tid];
      float mx = sc;
      #pragma unroll
      for(int m=1;m<32;m<<=1) mx = fmaxf(mx, __shfl_xor(mx, m, 64));
      float e = __expf(sc - mx);
      float sm = e;
      #pragma unroll
      for(int m=1;m<32;m<<=1) sm += __shfl_xor(sm, m, 64);
      alw[tid] = e/sm;
    }
    __syncthreads();
    // ctx: 4 cols per thread (float4 enc loads)
    {
      int cc = tid*4;
      const float* eb = enc + (size_t)b*32768;
      f4v c4; c4[0]=0.f; c4[1]=0.f; c4[2]=0.f; c4[3]=0.f;
      for(int s=0;s<32;++s){
        float al = alw[s];
        f4v e4 = *(const f4v*)&eb[(size_t)s*1024 + cc];
        c4 += e4 * al;
      }
      *(f4v*)&ctxX[(size_t)(t+1)*65536 + (size_t)b*1024 + cc] = c4;
      u16 x0=f2bf(c4[0]), x1=f2bf(c4[1]), x2=f2bf(c4[2]), x3=f2bf(c4[3]);
      uint2 pk; pk.x = (unsigned)x0 | ((unsigned)x1<<16); pk.y = (unsigned)x2 | ((unsigned)x3<<16);
      *(uint2*)&hhi[(size_t)b*1536 + 512 + cc] = pk;
      u16 y0=f2bf(c4[0]-bf2f(x0)), y1=f2bf(c4[1]-bf2f(x1));
      u16 y2=f2bf(c4[2]-bf2f(x2)), y3=f2bf(c4[3]-bf2f(x3));
      uint2 pl; pl.x = (unsigned)y0 | ((unsigned)y1<<16); pl.y = (unsigned)y2 | ((unsigned)y3<<16);
      *(uint2*)&hlo[(size_t)b*1536 + 512 + cc] = pl;
    }
  }
}

// ---------- host ----------
extern "C" void kernel_launch(void* const* d_in, const int* in_sizes, int n_in,
                              void* d_out, int out_size, void* d_ws, size_t ws_size,
                              hipStream_t stream){
  const int*   dec = (const int*)d_in[0];
  const float* enc = (const float*)d_in[1];
  const float* eh  = (const float*)d_in[2];
  const float* ec  = (const float*)d_in[3];
  const float* emb = (const float*)d_in[4];
  const float* Wx  = (const float*)d_in[5];
  const float* Uh  = (const float*)d_in[6];
  const float* bb  = (const float*)d_in[7];
  const float* Wm  = (const float*)d_in[8];
  const float* Wq  = (const float*)d_in[9];
  const float* vv  = (const float*)d_in[10];
  const float* Wa  = (const float*)d_in[11];
  const float* Wf  = (const float*)d_in[12];
  const float* bf  = (const float*)d_in[13];
  float* out = (float*)d_out;

  // ---- workspace carving ----
  char* w = (char*)d_ws; size_t off = 0;
  auto alloc = [&](size_t bytes)->char*{ char* p = w + off; off = (off + bytes + 255) & ~(size_t)255; return p; };
  u16* WfT   = (u16*)alloc((size_t)34004*512*2);
  u16* attn2 = (u16*)alloc((size_t)3776*512*2);
  size_t liveEnd = off;
  const size_t needB = (size_t)131<<20;
  bool fits = (ws_size >= liveEnd + needB);
  char* wb = fits ? (w + liveEnd) : (char*)d_out;
  size_t offb = 0;
  auto allocB = [&](size_t bytes)->char*{ char* p = wb + offb; offb = (offb + bytes + 255) & ~(size_t)255; return p; };

  u16* wzT   = (u16*)allocB((size_t)2048*3072*2);
  u16* buhT  = (u16*)allocB((size_t)2048*1024*2);
  u16* wqB   = (u16*)allocB((size_t)512*512*2);
  u16* waT   = (u16*)allocB((size_t)512*1536*2);
  u16* wmT   = (u16*)allocB((size_t)512*1024*2);
  u16* wxtpT = (u16*)allocB((size_t)2048*320*2);
  u16* wxaT  = (u16*)allocB((size_t)2048*1536*2);
  u16* waA   = (u16*)allocB((size_t)1536*1536*2);
  float* wzc = (float*)allocB((size_t)2048*1536*4);
  u16* embB  = (u16*)allocB((size_t)3776*320*2);
  u16* encB  = (u16*)allocB((size_t)2048*1024*2);
  float* Zemb  = (float*)allocB((size_t)3776*2048*4);
  float* keys  = (float*)allocB((size_t)2048*512*4);
  float* zparts= (float*)allocB((size_t)9*64*2048*4);
  float* h2X   = (float*)allocB((size_t)60*64*512*4);
  float* ctxX  = (float*)allocB((size_t)60*64*1024*4);
  float* cst   = (float*)allocB((size_t)64*512*4);
  float* bp    = (float*)allocB((size_t)2048*4);
  u16* A2c   = (u16*)allocB((size_t)3776*1536*2);
  u16* hhi   = (u16*)allocB((size_t)64*1536*2);
  u16* hlo   = (u16*)allocB((size_t)64*1536*2);
  unsigned* flags = (unsigned*)allocB((size_t)59*512*4);

  // ---- precompute ----
  k_init<<<638,256,0,stream>>>(bb, eh, ec, bp, h2X, cst, ctxX, flags);
  k_hinit<<<384,256,0,stream>>>(eh, hhi, hlo);
  k_embgather<<<(3776*40+255)/256,256,0,stream>>>(dec, emb, embB);
  k_cvt<<<(262144+255)/256,256,0,stream>>>(enc, encB, 262144);
  k_cvt<<<(32768+255)/256,256,0,stream>>>(Wq, wqB, 32768);
  k_wmT<<<(512*128+255)/256,256,0,stream>>>(Wm, wmT);
  k_waT<<<(512*192+255)/256,256,0,stream>>>(Wa, waT);
  k_wxtpT<<<(2048*40+255)/256,256,0,stream>>>(Wx, wxtpT);
  k_wxaT<<<(2048*192+255)/256,256,0,stream>>>(Wx, wxaT);
  k_buhT<<<(2048*128+255)/256,256,0,stream>>>(Uh, buhT);
  k_waA<<<(1536*192+255)/256,256,0,stream>>>(Wa, waA);
  k_wfT<<<dim3(532,8),256,0,stream>>>(Wf, WfT);

  // Zemb = gather(emb) @ Wx_top (slot cols) + b   [3776][2048]
  gemm_bf16<1><<<dim3(16,30),256,0,stream>>>(embB, wxtpT, 3776, 2048, 320, Zemb, nullptr, bp, nullptr);
  // keys = enc @ Wm  [2048][512]
  gemm_bf16<0><<<dim3(4,16),256,0,stream>>>(encB, wmT, 2048, 512, 1024, keys, nullptr, nullptr, nullptr);
  // WzcT = Wx_att^T @ Wa^T (transposed composite, split-precision)  [2048 pc][1536 r]
  gemm_bf16<0><<<dim3(12,16),256,0,stream>>>(wxaT, waA, 2048, 1536, 1536, wzc, nullptr, nullptr, nullptr);
  // W'z^T = split( WzcT + Uh(top) )^T   [2048][3072]
  k_wzcT<<<(2048*384+255)/256,256,0,stream>>>(wzc, Uh, wzT);

  // ---- recurrence: ONE fused launch per step ----
  for (int t=0; t<59; ++t){
    step_fused<<<512,256,0,stream>>>(t, wzT, buhT, hhi, hlo, zparts, Zemb,
                                     cst, h2X, ctxX, wqB, keys, enc, vv, flags);
  }

  // ---- deferred attn2 + logits ----
  k_a2dump<<<(3776*192+255)/256,256,0,stream>>>(h2X, ctxX, A2c);
  gemm_bf16<2><<<dim3(4,30),256,0,stream>>>(A2c, waT, 3776, 512, 1536, nullptr, attn2, nullptr, nullptr);
  gemm_bf16<3><<<dim3(266,30),256,0,stream>>>(attn2, WfT, 3776, 34004, 512, nullptr, nullptr, bf, out);
}

// Round 8
// 1918.398 us; speedup vs baseline: 2.4973x; 1.4851x over previous
//
#include <hip/hip_runtime.h>
#include <hip/hip_bf16.h>
#include <cstdint>
#include <cstddef>

typedef unsigned short u16;
typedef unsigned long long u64;
typedef short s8v __attribute__((ext_vector_type(8)));
typedef float f4v __attribute__((ext_vector_type(4)));

#define DI __device__ __forceinline__

// ---------- helpers ----------
DI u16 f2bf(float f){ unsigned u = __float_as_uint(f); u += 0x7fffu + ((u>>16)&1u); return (u16)(u>>16); }
DI float bf2f(u16 h){ return __uint_as_float(((unsigned)h)<<16); }
DI int ocol(int pc){ return ((pc>>3)&3)*512 + (pc>>5)*8 + (pc&7); }  // packed col -> original col
// slot layout (gate-contiguous): slot s = hb*32 + jj*4 + g  ->  original col
DI int ocol2(int s){ int pc = (s & ~31) | ((s&3)<<3) | ((s>>2)&7); return ocol(pc); }
DI int pc2slot(int pc){ return (pc & ~31) | ((pc&7)<<2) | ((pc>>3)&3); }
DI float sigm(float x){ x = fminf(fmaxf(x,-30.f),30.f); return 1.f/(1.f+__expf(-x)); }
DI float tanhx(float x){ x = fminf(fmaxf(x,-15.f),15.f); float e = __expf(-2.f*x); return (1.f-e)/(1.f+e); }
DI uint4 packh8(const u16* h){
  uint4 r; r.x=(unsigned)h[0]|((unsigned)h[1]<<16); r.y=(unsigned)h[2]|((unsigned)h[3]<<16);
  r.z=(unsigned)h[4]|((unsigned)h[5]<<16); r.w=(unsigned)h[6]|((unsigned)h[7]<<16); return r;
}
DI void unp8(uint4 w, float* o){
  o[0]=bf2f((u16)(w.x&0xffffu)); o[1]=bf2f((u16)(w.x>>16));
  o[2]=bf2f((u16)(w.y&0xffffu)); o[3]=bf2f((u16)(w.y>>16));
  o[4]=bf2f((u16)(w.z&0xffffu)); o[5]=bf2f((u16)(w.z>>16));
  o[6]=bf2f((u16)(w.w&0xffffu)); o[7]=bf2f((u16)(w.w>>16));
}
DI s8v u4s8(uint4 u){ union{uint4 a; s8v b;} t; t.a=u; return t.b; }

// ---------- agent-coherent (fence-free) access helpers ----------
DI unsigned cohld32(const void* p){
  return __hip_atomic_load((const unsigned*)p, __ATOMIC_RELAXED, __HIP_MEMORY_SCOPE_AGENT);
}
DI u64 cohld64(const void* p){
  return __hip_atomic_load((const u64*)p, __ATOMIC_RELAXED, __HIP_MEMORY_SCOPE_AGENT);
}
DI f4v cohldf4(const float* p){
  u64 lo = cohld64(p);
  u64 hi = cohld64(p + 2);
  f4v r;
  r[0]=__uint_as_float((unsigned)lo); r[1]=__uint_as_float((unsigned)(lo>>32));
  r[2]=__uint_as_float((unsigned)hi); r[3]=__uint_as_float((unsigned)(hi>>32));
  return r;
}
DI void cohst32(void* p, unsigned v){
  __hip_atomic_store((unsigned*)p, v, __ATOMIC_RELAXED, __HIP_MEMORY_SCOPE_AGENT);
}
DI void cohst64(void* p, u64 v){
  __hip_atomic_store((u64*)p, v, __ATOMIC_RELAXED, __HIP_MEMORY_SCOPE_AGENT);
}

// ---------- small builder kernels ----------
__global__ void k_init(const float* bb, const float* eh, const float* ec,
                       float* bp, float* h2X, float* cst, float* ctxX, unsigned* flags){
  int i = blockIdx.x*256 + threadIdx.x;
  if (i < 2048) bp[i] = bb[ocol2(i)];
  else if (i < 2048+32768) h2X[i-2048] = eh[i-2048];
  else if (i < 2048+65536) cst[i-34816] = ec[i-34816];
  else if (i < 2048+131072) ctxX[i-67584] = 0.f;
  else if (i < 2048+131072+30208) flags[i-133120] = 0u;
}

// hcat = [h0 | zeros] as bf16 hi/lo split, rows b, 1536 cols
__global__ void k_hinit(const float* __restrict__ eh, u16* __restrict__ hhi, u16* __restrict__ hlo){
  int i = blockIdx.x*256 + threadIdx.x; if (i >= 64*1536) return;
  int c = i % 1536;
  float f = (c < 512) ? eh[(i/1536)*512 + c] : 0.f;
  u16 hi = f2bf(f);
  hhi[i] = hi;
  hlo[i] = (c < 512) ? f2bf(f - bf2f(hi)) : (u16)0;
}

__global__ void k_cvt(const float* __restrict__ src, u16* __restrict__ dst, int octs){
  int g = blockIdx.x*256 + threadIdx.x; if (g >= octs) return;
  const float4* p = (const float4*)(src + (size_t)g*8);
  float4 a = p[0], b = p[1];
  u16 h[8] = {f2bf(a.x),f2bf(a.y),f2bf(a.z),f2bf(a.w),f2bf(b.x),f2bf(b.y),f2bf(b.z),f2bf(b.w)};
  *(uint4*)&dst[(size_t)g*8] = packh8(h);
}

__global__ void k_embgather(const int* __restrict__ dec, const float* __restrict__ emb, u16* __restrict__ dst){
  int g = blockIdx.x*256 + threadIdx.x; if (g >= 3776*40) return;
  int row = g/40, o = g%40;
  int b = row & 63, t = row >> 6;
  int tok = dec[b*59 + t];
  u16 h[8];
  #pragma unroll
  for(int j=0;j<8;++j){ int k = o*8+j; float f = (k<300)? emb[(size_t)tok*300 + k] : 0.f; h[j]=f2bf(f); }
  *(uint4*)&dst[(size_t)row*320 + o*8] = packh8(h);
}

__global__ void k_wmT(const float* __restrict__ Wm, u16* __restrict__ dst){
  int g = blockIdx.x*256 + threadIdx.x; if (g >= 512*128) return;
  int hcol = g/128, o = g%128;
  u16 h[8];
  #pragma unroll
  for(int j=0;j<8;++j){ int m = o*8+j; h[j]=f2bf(Wm[(size_t)m*512 + hcol]); }
  *(uint4*)&dst[(size_t)hcol*1024 + o*8] = packh8(h);
}

__global__ void k_waT(const float* __restrict__ Wa, u16* __restrict__ dst){
  int g = blockIdx.x*256 + threadIdx.x; if (g >= 512*192) return;
  int c = g/192, o = g%192;
  u16 h[8];
  #pragma unroll
  for(int j=0;j<8;++j){ int k = o*8+j; h[j]=f2bf(Wa[(size_t)k*512 + c]); }
  *(uint4*)&dst[(size_t)c*1536 + o*8] = packh8(h);
}

// Wx top rows (emb part), cols in slot (gate-contiguous) order -> Zemb lands gate-contiguous
__global__ void k_wxtpT(const float* __restrict__ Wx, u16* __restrict__ dst){
  int g = blockIdx.x*256 + threadIdx.x; if (g >= 2048*40) return;
  int pc = g/40, o = g%40; int oc = ocol2(pc);
  u16 h[8];
  #pragma unroll
  for(int j=0;j<8;++j){ int e = o*8+j; float f = (e<300)? Wx[(size_t)e*2048 + oc] : 0.f; h[j]=f2bf(f); }
  *(uint4*)&dst[(size_t)pc*320 + o*8] = packh8(h);
}

// Wx_att^T splits: segs [hi(512) | hi(512) | lo(512)] along k'  (packed-pc cols)
__global__ void k_wxaT(const float* __restrict__ Wx, u16* __restrict__ dst){
  int g = blockIdx.x*256 + threadIdx.x; if (g >= 2048*192) return;
  int pc = g/192, o = g%192; int oc = ocol(pc);
  u16 h[8];
  #pragma unroll
  for(int j=0;j<8;++j){
    int kp = o*8+j; int seg = kp>>9; int jd = kp&511;
    float f = Wx[(size_t)(300+jd)*2048 + oc];
    u16 hi = f2bf(f);
    h[j] = (seg==2) ? f2bf(f - bf2f(hi)) : hi;
  }
  *(uint4*)&dst[(size_t)pc*1536 + o*8] = packh8(h);
}

// Wa splits (A side of composite GEMM): segs [hi | lo | hi]
__global__ void k_waA(const float* __restrict__ Wa, u16* __restrict__ dst){
  int g = blockIdx.x*256 + threadIdx.x; if (g >= 1536*192) return;
  int r = g/192, o = g%192;
  u16 h[8];
  #pragma unroll
  for(int j=0;j<8;++j){
    int kp = o*8+j; int seg = kp>>9; int jd = kp&511;
    float f = Wa[(size_t)r*512 + jd];
    u16 hi = f2bf(f);
    h[j] = (seg==1) ? f2bf(f - bf2f(hi)) : hi;
  }
  *(uint4*)&dst[(size_t)r*1536 + o*8] = packh8(h);
}

// Uh^T packed splits: phys [hi(512) | lo(512)]
__global__ void k_buhT(const float* __restrict__ Uh, u16* __restrict__ dst){
  int g = blockIdx.x*256 + threadIdx.x; if (g >= 2048*128) return;
  int pc = g/128, o = g%128; int oc = ocol(pc);
  u16 h[8];
  #pragma unroll
  for(int j=0;j<8;++j){
    int kp = o*8+j; int r = kp&511;
    float f = Uh[(size_t)r*2048 + oc];
    u16 hi = f2bf(f);
    h[j] = (kp<512) ? hi : f2bf(f - bf2f(hi));
  }
  *(uint4*)&dst[(size_t)pc*1024 + o*8] = packh8(h);
}

// (WzcT + Uh-on-top)^T splits: phys [hi(1536) | lo(1536)]
// wzcT is [2048 pc][1536 r]  (transposed composite) -> row-coalesced reads
__global__ void k_wzcT(const float* __restrict__ wzcT, const float* __restrict__ Uh, u16* __restrict__ dst){
  int g = blockIdx.x*256 + threadIdx.x; if (g >= 2048*384) return;
  int pc = g/384, o = g%384; int oc = ocol(pc);
  u16 h[8];
  #pragma unroll
  for(int j=0;j<8;++j){
    int kp = o*8+j; int r = kp % 1536;
    float f = wzcT[(size_t)pc*1536 + r] + ((r<512) ? Uh[(size_t)r*2048 + oc] : 0.f);
    u16 hi = f2bf(f);
    h[j] = (kp<1536) ? hi : f2bf(f - bf2f(hi));
  }
  *(uint4*)&dst[(size_t)pc*3072 + o*8] = packh8(h);
}

// A2cat = [h2 | ctx] bf16, rows r = t*64+b  (reads slot t+1 == row r+64)
__global__ void k_a2dump(const float* __restrict__ h2X, const float* __restrict__ ctxX, u16* __restrict__ dst){
  int g = blockIdx.x*256 + threadIdx.x; if (g >= 3776*192) return;
  int r = g/192, o = g%192;
  u16 h[8];
  #pragma unroll
  for(int j=0;j<8;++j){
    int k = o*8+j;
    float f = (k<512) ? h2X[(size_t)(r+64)*512 + k] : ctxX[(size_t)(r+64)*1024 + (k-512)];
    h[j] = f2bf(f);
  }
  *(uint4*)&dst[(size_t)r*1536 + o*8] = packh8(h);
}

// Wf [512][34004] f32 -> WfT [34004][512] bf16 (LDS-tiled transpose)
__global__ __launch_bounds__(256) void k_wfT(const float* __restrict__ Wf, u16* __restrict__ WfT){
  __shared__ u16 T[64*72];
  int n0 = blockIdx.x*64, k0 = blockIdx.y*64;
  int tid = threadIdx.x;
  int kl = tid>>2, nq = (tid&3)*16;
  u16 h[16];
  if (n0 + 64 <= 34004){
    const float4* p = (const float4*)(Wf + (size_t)(k0+kl)*34004 + n0 + nq);
    #pragma unroll
    for(int q=0;q<4;++q){ float4 f = p[q]; h[q*4+0]=f2bf(f.x); h[q*4+1]=f2bf(f.y); h[q*4+2]=f2bf(f.z); h[q*4+3]=f2bf(f.w); }
  } else {
    #pragma unroll
    for(int j=0;j<16;++j){ int n = n0+nq+j; float f = (n<34004)? Wf[(size_t)(k0+kl)*34004 + n] : 0.f; h[j]=f2bf(f); }
  }
  *(uint4*)&T[kl*72 + nq] = packh8(h);
  *(uint4*)&T[kl*72 + nq + 8] = packh8(h+8);
  __syncthreads();
  int nl = tid>>2, kq = (tid&3)*16;
  int n = n0 + nl;
  if (n < 34004){
    u16 o[16];
    #pragma unroll
    for(int j=0;j<16;++j) o[j] = T[(kq+j)*72 + nl];
    *(uint4*)&WfT[(size_t)n*512 + k0 + kq]     = packh8(o);
    *(uint4*)&WfT[(size_t)n*512 + k0 + kq + 8] = packh8(o+8);
  }
}

// ---------- generic 128x128 bf16 MFMA GEMM:  C[M,N] = A[M,K] * Bt[N,K]^T ----------
template<int EPI>
__global__ __launch_bounds__(256,2) void gemm_bf16(
    const u16* __restrict__ A, const u16* __restrict__ Bt,
    int M, int N, int K,
    float* __restrict__ Cf, u16* __restrict__ Cb,
    const float* __restrict__ bias, float* __restrict__ Cout){
  __shared__ u16 LSbuf[2*128*40];
  u16* Als = LSbuf;
  u16* Bls = LSbuf + 128*40;
  int tid = threadIdx.x;
  int c0 = blockIdx.x*128, r0 = blockIdx.y*128;
  int wid = tid>>6, wr = wid>>1, wc = wid&1;
  int l15 = tid&15, l4 = (tid>>4)&3;
  f4v acc[4][4];
  #pragma unroll
  for(int m=0;m<4;++m)
  #pragma unroll
  for(int n=0;n<4;++n)
  #pragma unroll
  for(int i=0;i<4;++i) acc[m][n][i] = 0.f;

  int r = tid>>1, hf = tid&1;
  size_t arow = (size_t)min(r0 + r, M-1);
  size_t brow = (size_t)min(c0 + r, N-1);
  const u16* abase = A  + arow*K + hf*16;
  const u16* bbase = Bt + brow*K + hf*16;
  int nk = K >> 5;
  uint4 a0 = ((const uint4*)abase)[0], a1 = ((const uint4*)abase)[1];
  uint4 b0 = ((const uint4*)bbase)[0], b1 = ((const uint4*)bbase)[1];
  for (int ch=0; ch<nk; ++ch){
    __syncthreads();
    *(uint4*)&Als[r*40 + hf*16]     = a0;
    *(uint4*)&Als[r*40 + hf*16 + 8] = a1;
    *(uint4*)&Bls[r*40 + hf*16]     = b0;
    *(uint4*)&Bls[r*40 + hf*16 + 8] = b1;
    __syncthreads();
    if (ch+1 < nk){
      const uint4* ap = (const uint4*)(abase + (ch+1)*32);
      const uint4* bp = (const uint4*)(bbase + (ch+1)*32);
      a0 = ap[0]; a1 = ap[1]; b0 = bp[0]; b1 = bp[1];
    }
    s8v af[4], bfr[4];
    #pragma unroll
    for(int m=0;m<4;++m) af[m]  = *(const s8v*)&Als[(wr*64 + m*16 + l15)*40 + l4*8];
    #pragma unroll
    for(int n=0;n<4;++n) bfr[n] = *(const s8v*)&Bls[(wc*64 + n*16 + l15)*40 + l4*8];
    #pragma unroll
    for(int m=0;m<4;++m)
    #pragma unroll
    for(int n=0;n<4;++n)
      acc[m][n] = __builtin_amdgcn_mfma_f32_16x16x32_bf16(af[m], bfr[n], acc[m][n], 0,0,0);
  }
  // epilogue: LDS-staged transpose to full-line float4 stores
  __syncthreads();
  float* eps = ((float*)LSbuf) + wid*1024;   // 16 rows x 64 cols per wave
  #pragma unroll
  for(int m=0;m<4;++m){
    #pragma unroll
    for(int n=0;n<4;++n)
    #pragma unroll
    for(int i=0;i<4;++i)
      eps[(l4*4 + i)*64 + n*16 + l15] = acc[m][n][i];
    #pragma unroll
    for(int q=0;q<4;++q){
      int row = l4 + q*4;
      f4v v = *(const f4v*)&eps[row*64 + l15*4];
      int gr = r0 + wr*64 + m*16 + row;
      int gc = c0 + wc*64 + l15*4;
      if (gr < M && gc < N){
        if constexpr (EPI==0){
          *(f4v*)&Cf[(size_t)gr*N + gc] = v;
        } else if constexpr (EPI==1){
          f4v bv = *(const f4v*)&bias[gc];
          v += bv;
          *(f4v*)&Cf[(size_t)gr*N + gc] = v;
        } else if constexpr (EPI==2){
          unsigned p0 = ((unsigned)f2bf(v[1])<<16) | f2bf(v[0]);
          unsigned p1 = ((unsigned)f2bf(v[3])<<16) | f2bf(v[2]);
          uint2 pk; pk.x = p0; pk.y = p1;
          *(uint2*)&Cb[(size_t)gr*N + gc] = pk;
        } else {
          f4v bv = *(const f4v*)&bias[gc];
          v += bv;
          int b_ = gr&63, tt = gr>>6;
          *(f4v*)&Cout[((size_t)(b_*59 + tt))*34004 + gc] = v;
        }
      }
    }
  }
}

// ---------- fused per-step kernel: z-GEMM + aggregator-sync + LSTM/attention ----------
// ONE launch per step, grid 320 x 512 threads. Capacity: 64KB LDS + <=128 VGPR
// (__launch_bounds__(512,4)) -> 2 blocks/CU x 256 CU = 512 >= 320, so all blocks
// are co-resident regardless of dispatch order (no deadlock).
// blocks 0..255: z-GEMM, 64 col-groups (32 pc) x 4 K-slices, 8 waves K-interleaved.
//   A = hcat (hhi/hlo) NORMAL cached loads (fresh via launch boundary); B normal
//   (L2-resident). zparts (natural pc order) via relaxed agent stores; vmcnt
//   drain; per-block flag (plain coherent store, no RMW).
// blocks 256..319 (one per batch): block b=0 aggregates the 256 flags (256
//   pollers, 1 flag each), publishes one done-flag; other blocks poll that single
//   word with one thread -> ~100x less poll traffic than r7. Then: coherent
//   zparts gather (4-deep), LDS slot-scatter, LSTM + q + scores + softmax + ctx
//   at round-2's proven 512-thread widths; state written with NORMAL stores.
__global__ __launch_bounds__(512,4) void step_fused(
    int t,
    const u16* __restrict__ wzT, const u16* __restrict__ buhT,
    u16* __restrict__ hhi, u16* __restrict__ hlo,
    float* __restrict__ zparts, const float* __restrict__ Zemb,
    float* __restrict__ cst, float* __restrict__ h2X, float* __restrict__ ctxX,
    const u16* __restrict__ wqB, const float* __restrict__ keys,
    const float* __restrict__ enc, const float* __restrict__ vv,
    unsigned* __restrict__ flags){
  __shared__ float smem[16384];   // 64 KB
  int bid = blockIdx.x, tid = threadIdx.x;
  unsigned* flg = flags + (size_t)t*512;
  int variant = (t==0) ? 0 : 1;

  if (bid < 256){
    // ---- z-GEMM block ----
    int sl = bid>>6, cg = bid&63;
    int pc0 = cg*32;
    int wv = tid>>6, lane = tid&63;
    int l15 = lane&15, l4 = lane>>4;
    const u16* Bt = variant ? wzT : buhT;
    int physK = variant ? 3072 : 1024;
    int CS = variant ? 36 : 12;        // K-chunks per slice (virtualK/32/4)
    int ck0 = sl*CS, ck1 = ck0 + CS;

    f4v acc[4][2];
    #pragma unroll
    for(int m=0;m<4;++m)
    #pragma unroll
    for(int n=0;n<2;++n)
    #pragma unroll
    for(int i=0;i<4;++i) acc[m][n][i] = 0.f;

    for (int c = ck0 + wv; c < ck1; c += 8){
      int k1 = c*32;
      const u16* ap; int inner, kB;
      if (variant==0){
        inner = k1 & 511;
        ap = ((((k1>>9)&3)==1) ? hlo : hhi);
        kB = (k1 < 1024) ? (k1 & 511) : (k1 - 512);
      } else {
        int sg = k1/1536; inner = k1 - sg*1536;
        ap = (sg==1) ? hlo : hhi;
        kB = (k1 < 3072) ? (k1 % 1536) : (1536 + (k1 - 3072));
      }
      uint4 av[4], bv[2];
      #pragma unroll
      for(int m=0;m<4;++m)
        av[m] = *(const uint4*)(ap + (size_t)(m*16 + l15)*1536 + inner + l4*8);
      #pragma unroll
      for(int n=0;n<2;++n)
        bv[n] = *(const uint4*)(Bt + (size_t)(pc0 + n*16 + l15)*physK + kB + l4*8);
      #pragma unroll
      for(int m=0;m<4;++m){
        s8v am = u4s8(av[m]);
        #pragma unroll
        for(int n=0;n<2;++n)
          acc[m][n] = __builtin_amdgcn_mfma_f32_16x16x32_bf16(am, u4s8(bv[n]), acc[m][n], 0,0,0);
      }
    }
    // LDS reduce across the 8 K-interleaved waves
    float* red = smem + wv*2048;
    #pragma unroll
    for(int m=0;m<4;++m)
    #pragma unroll
    for(int n=0;n<2;++n)
    #pragma unroll
    for(int i=0;i<4;++i)
      red[(m*16 + l4*4 + i)*32 + n*16 + l15] = acc[m][n][i];
    __syncthreads();

    int rr = tid>>3, cq = (tid&7)*4;
    f4v s = *(const f4v*)&smem[rr*32 + cq];
    #pragma unroll
    for(int w=1;w<8;++w)
      s += *(const f4v*)&smem[w*2048 + rr*32 + cq];
    float* zp = zparts + (size_t)sl*131072 + (size_t)rr*2048 + pc0 + cq;
    cohst64(&zp[0], (u64)__float_as_uint(s[0]) | ((u64)__float_as_uint(s[1])<<32));
    cohst64(&zp[2], (u64)__float_as_uint(s[2]) | ((u64)__float_as_uint(s[3])<<32));
    asm volatile("s_waitcnt vmcnt(0)" ::: "memory");
    __syncthreads();
    if (tid==0) cohst32(&flg[bid], 1u);

  } else {
    // ---- attention block (one per batch) ----
    int b = bid - 256;
    // prefetch step-t inputs that do NOT depend on z (hides latency under wait)
    int j = tid;
    int base = (j>>3)*32 + (j&7)*4;            // gate-slot base for unit j
    f4v ze = *(const f4v*)&Zemb[(size_t)t*131072 + (size_t)b*2048 + base];
    float cprev = cst[(size_t)b*512 + j];
    float vvj = vv[j];
    // sync: b0 aggregates 256 flags, publishes one done word; others poll it
    if (b == 0){
      if (tid < 256){
        while (cohld32(&flg[tid]) == 0u) __builtin_amdgcn_s_sleep(2);
      }
      __syncthreads();
      if (tid==0) cohst32(&flg[511], 1u);
    } else {
      if (tid==0){
        while (cohld32(&flg[511]) == 0u) __builtin_amdgcn_s_sleep(1);
      }
      __syncthreads();
    }
    asm volatile("" ::: "memory");

    float* zl  = smem;            // 2048
    float* h2s = smem + 2048;     // 512
    float* vs2 = smem + 2560;     // 512
    float* qs  = smem + 3072;     // 512
    float* qpl = smem + 3584;     // 4096
    float* scl = smem + 7680;     // 32
    float* alw = smem + 7712;     // 32
    // z-sum gather (coherent, 4-deep) + LDS slot-scatter
    {
      int p4 = tid*4;
      f4v z0; z0[0]=0.f; z0[1]=0.f; z0[2]=0.f; z0[3]=0.f;
      #pragma unroll
      for(int s2=0; s2<4; ++s2)
        z0 += cohldf4(&zparts[(size_t)s2*131072 + (size_t)b*2048 + p4]);
      #pragma unroll
      for(int e=0;e<4;++e)
        zl[pc2slot(p4+e)] = z0[e];
    }
    __syncthreads();
    // LSTM: one unit per thread
    {
      f4v s4 = ze + *(const f4v*)&zl[base];
      float c2 = sigm(s4[1])*cprev + sigm(s4[0])*tanhx(s4[2]);
      float h2 = sigm(s4[3])*tanhx(c2);
      cst[(size_t)b*512 + j] = c2;
      h2X[(size_t)(t+1)*32768 + (size_t)b*512 + j] = h2;
      h2s[j] = h2; vs2[j] = vvj;
      u16 hh2 = f2bf(h2);
      hhi[(size_t)b*1536 + j] = hh2;
      hlo[(size_t)b*1536 + j] = f2bf(h2 - bf2f(hh2));
    }
    __syncthreads();
    // q = h2 @ Wq  (8 h-slices x 64 threads x 8 cols -- round-2 widths)
    {
      int c8 = (tid&63)*8, hs = tid>>6;
      float qp[8] = {0,0,0,0,0,0,0,0};
      for(int hh=0; hh<64; ++hh){
        int h = hs*64 + hh;
        float w[8]; unp8(*(const uint4*)(wqB + (size_t)h*512 + c8), w);
        float hv = h2s[h];
        #pragma unroll
        for(int q=0;q<8;++q) qp[q] += hv*w[q];
      }
      *(float4*)&qpl[hs*512 + c8]     = make_float4(qp[0],qp[1],qp[2],qp[3]);
      *(float4*)&qpl[hs*512 + c8 + 4] = make_float4(qp[4],qp[5],qp[6],qp[7]);
    }
    __syncthreads();
    { float s = 0.f; for(int hs=0; hs<8; ++hs) s += qpl[hs*512 + tid]; qs[tid] = s; }
    __syncthreads();
    // scores: 16 threads per s (32 s), 32 h each, float4 keys
    {
      int s = tid>>4, hh = tid&15;
      const float4* kb4 = (const float4*)(keys + ((size_t)(b*32 + s))*512 + hh*32);
      float part = 0.f;
      #pragma unroll
      for(int i8=0;i8<8;++i8){
        float4 kv = kb4[i8];
        int h = hh*32 + i8*4;
        part += vs2[h+0]*tanhx(kv.x + qs[h+0]);
        part += vs2[h+1]*tanhx(kv.y + qs[h+1]);
        part += vs2[h+2]*tanhx(kv.z + qs[h+2]);
        part += vs2[h+3]*tanhx(kv.w + qs[h+3]);
      }
      #pragma unroll
      for(int m=1;m<16;m<<=1) part += __shfl_xor(part, m, 64);
      if (hh==0) scl[s] = part;
    }
    __syncthreads();
    // softmax over 32
    if (tid < 32){
      float sc = scl[tid];
      float mx = sc;
      #pragma unroll
      for(int m=1;m<32;m<<=1) mx = fmaxf(mx, __shfl_xor(mx, m, 64));
      float e = __expf(sc - mx);
      float sm = e;
      #pragma unroll
      for(int m=1;m<32;m<<=1) sm += __shfl_xor(sm, m, 64);
      alw[tid] = e/sm;
    }
    __syncthreads();
    // ctx: 2 adjacent cols per thread (float2 enc loads)
    {
      const float* eb = enc + (size_t)b*32768;
      int cc = tid*2;
      float c0 = 0.f, c1 = 0.f;
      for(int s=0;s<32;++s){
        float al = alw[s];
        float2 e2 = *(const float2*)&eb[(size_t)s*1024 + cc];
        c0 += al*e2.x;
        c1 += al*e2.y;
      }
      float2 co; co.x = c0; co.y = c1;
      *(float2*)&ctxX[(size_t)(t+1)*65536 + (size_t)b*1024 + cc] = co;
      u16 x0 = f2bf(c0), x1 = f2bf(c1);
      *(unsigned*)&hhi[(size_t)b*1536 + 512 + cc] = (unsigned)x0 | ((unsigned)x1<<16);
      u16 y0 = f2bf(c0 - bf2f(x0)), y1 = f2bf(c1 - bf2f(x1));
      *(unsigned*)&hlo[(size_t)b*1536 + 512 + cc] = (unsigned)y0 | ((unsigned)y1<<16);
    }
  }
}

// ---------- host ----------
extern "C" void kernel_launch(void* const* d_in, const int* in_sizes, int n_in,
                              void* d_out, int out_size, void* d_ws, size_t ws_size,
                              hipStream_t stream){
  const int*   dec = (const int*)d_in[0];
  const float* enc = (const float*)d_in[1];
  const float* eh  = (const float*)d_in[2];
  const float* ec  = (const float*)d_in[3];
  const float* emb = (const float*)d_in[4];
  const float* Wx  = (const float*)d_in[5];
  const float* Uh  = (const float*)d_in[6];
  const float* bb  = (const float*)d_in[7];
  const float* Wm  = (const float*)d_in[8];
  const float* Wq  = (const float*)d_in[9];
  const float* vv  = (const float*)d_in[10];
  const float* Wa  = (const float*)d_in[11];
  const float* Wf  = (const float*)d_in[12];
  const float* bf  = (const float*)d_in[13];
  float* out = (float*)d_out;

  // ---- workspace carving ----
  char* w = (char*)d_ws; size_t off = 0;
  auto alloc = [&](size_t bytes)->char*{ char* p = w + off; off = (off + bytes + 255) & ~(size_t)255; return p; };
  u16* WfT   = (u16*)alloc((size_t)34004*512*2);
  u16* attn2 = (u16*)alloc((size_t)3776*512*2);
  size_t liveEnd = off;
  const size_t needB = (size_t)131<<20;
  bool fits = (ws_size >= liveEnd + needB);
  char* wb = fits ? (w + liveEnd) : (char*)d_out;
  size_t offb = 0;
  auto allocB = [&](size_t bytes)->char*{ char* p = wb + offb; offb = (offb + bytes + 255) & ~(size_t)255; return p; };

  u16* wzT   = (u16*)allocB((size_t)2048*3072*2);
  u16* buhT  = (u16*)allocB((size_t)2048*1024*2);
  u16* wqB   = (u16*)allocB((size_t)512*512*2);
  u16* waT   = (u16*)allocB((size_t)512*1536*2);
  u16* wmT   = (u16*)allocB((size_t)512*1024*2);
  u16* wxtpT = (u16*)allocB((size_t)2048*320*2);
  u16* wxaT  = (u16*)allocB((size_t)2048*1536*2);
  u16* waA   = (u16*)allocB((size_t)1536*1536*2);
  float* wzc = (float*)allocB((size_t)2048*1536*4);
  u16* embB  = (u16*)allocB((size_t)3776*320*2);
  u16* encB  = (u16*)allocB((size_t)2048*1024*2);
  float* Zemb  = (float*)allocB((size_t)3776*2048*4);
  float* keys  = (float*)allocB((size_t)2048*512*4);
  float* zparts= (float*)allocB((size_t)9*64*2048*4);
  float* h2X   = (float*)allocB((size_t)60*64*512*4);
  float* ctxX  = (float*)allocB((size_t)60*64*1024*4);
  float* cst   = (float*)allocB((size_t)64*512*4);
  float* bp    = (float*)allocB((size_t)2048*4);
  u16* A2c   = (u16*)allocB((size_t)3776*1536*2);
  u16* hhi   = (u16*)allocB((size_t)64*1536*2);
  u16* hlo   = (u16*)allocB((size_t)64*1536*2);
  unsigned* flags = (unsigned*)allocB((size_t)59*512*4);

  // ---- precompute ----
  k_init<<<638,256,0,stream>>>(bb, eh, ec, bp, h2X, cst, ctxX, flags);
  k_hinit<<<384,256,0,stream>>>(eh, hhi, hlo);
  k_embgather<<<(3776*40+255)/256,256,0,stream>>>(dec, emb, embB);
  k_cvt<<<(262144+255)/256,256,0,stream>>>(enc, encB, 262144);
  k_cvt<<<(32768+255)/256,256,0,stream>>>(Wq, wqB, 32768);
  k_wmT<<<(512*128+255)/256,256,0,stream>>>(Wm, wmT);
  k_waT<<<(512*192+255)/256,256,0,stream>>>(Wa, waT);
  k_wxtpT<<<(2048*40+255)/256,256,0,stream>>>(Wx, wxtpT);
  k_wxaT<<<(2048*192+255)/256,256,0,stream>>>(Wx, wxaT);
  k_buhT<<<(2048*128+255)/256,256,0,stream>>>(Uh, buhT);
  k_waA<<<(1536*192+255)/256,256,0,stream>>>(Wa, waA);
  k_wfT<<<dim3(532,8),256,0,stream>>>(Wf, WfT);

  // Zemb = gather(emb) @ Wx_top (slot cols) + b   [3776][2048]
  gemm_bf16<1><<<dim3(16,30),256,0,stream>>>(embB, wxtpT, 3776, 2048, 320, Zemb, nullptr, bp, nullptr);
  // keys = enc @ Wm  [2048][512]
  gemm_bf16<0><<<dim3(4,16),256,0,stream>>>(encB, wmT, 2048, 512, 1024, keys, nullptr, nullptr, nullptr);
  // WzcT = Wx_att^T @ Wa^T (transposed composite, split-precision)  [2048 pc][1536 r]
  gemm_bf16<0><<<dim3(12,16),256,0,stream>>>(wxaT, waA, 2048, 1536, 1536, wzc, nullptr, nullptr, nullptr);
  // W'z^T = split( WzcT + Uh(top) )^T   [2048][3072]
  k_wzcT<<<(2048*384+255)/256,256,0,stream>>>(wzc, Uh, wzT);

  // ---- recurrence: ONE fused launch per step ----
  for (int t=0; t<59; ++t){
    step_fused<<<320,512,0,stream>>>(t, wzT, buhT, hhi, hlo, zparts, Zemb,
                                     cst, h2X, ctxX, wqB, keys, enc, vv, flags);
  }

  // ---- deferred attn2 + logits ----
  k_a2dump<<<(3776*192+255)/256,256,0,stream>>>(h2X, ctxX, A2c);
  gemm_bf16<2><<<dim3(4,30),256,0,stream>>>(A2c, waT, 3776, 512, 1536, nullptr, attn2, nullptr, nullptr);
  gemm_bf16<3><<<dim3(266,30),256,0,stream>>>(attn2, WfT, 3776, 34004, 512, nullptr, nullptr, bf, out);
}

// Round 9
// 1719.913 us; speedup vs baseline: 2.7855x; 1.1154x over previous
//
#include <hip/hip_runtime.h>
#include <hip/hip_bf16.h>
#include <hip/hip_fp16.h>
#include <cstdint>
#include <cstddef>

typedef unsigned short u16;
typedef unsigned long long u64;
typedef short s8v __attribute__((ext_vector_type(8)));
typedef float f4v __attribute__((ext_vector_type(4)));
typedef _Float16 f16x2 __attribute__((ext_vector_type(2)));

#define DI __device__ __forceinline__

#if defined(__has_builtin)
#  if __has_builtin(__builtin_amdgcn_fdot2)
#    define HAS_FDOT2 1
#  endif
#endif

// ---------- helpers ----------
DI u16 f2bf(float f){ unsigned u = __float_as_uint(f); u += 0x7fffu + ((u>>16)&1u); return (u16)(u>>16); }
DI float bf2f(u16 h){ return __uint_as_float(((unsigned)h)<<16); }
DI int ocol(int pc){ return ((pc>>3)&3)*512 + (pc>>5)*8 + (pc&7); }  // packed col -> original col
// slot layout (gate-contiguous): slot s = hb*32 + jj*4 + g  ->  original col
DI int ocol2(int s){ int pc = (s & ~31) | ((s&3)<<3) | ((s>>2)&7); return ocol(pc); }
DI int pc2slot(int pc){ return (pc & ~31) | ((pc&7)<<2) | ((pc>>3)&3); }
DI float sigm(float x){ x = fminf(fmaxf(x,-30.f),30.f); return 1.f/(1.f+__expf(-x)); }
DI float tanhx(float x){ x = fminf(fmaxf(x,-15.f),15.f); float e = __expf(-2.f*x); return (1.f-e)/(1.f+e); }
DI uint4 packh8(const u16* h){
  uint4 r; r.x=(unsigned)h[0]|((unsigned)h[1]<<16); r.y=(unsigned)h[2]|((unsigned)h[3]<<16);
  r.z=(unsigned)h[4]|((unsigned)h[5]<<16); r.w=(unsigned)h[6]|((unsigned)h[7]<<16); return r;
}
DI s8v u4s8(uint4 u){ union{uint4 a; s8v b;} t; t.a=u; return t.b; }

// f16-pair dot: acc += w.lo*hv.lo + w.hi*hv.hi
DI float qdot(unsigned w, f16x2 hv, float acc){
#ifdef HAS_FDOT2
  f16x2 wv; __builtin_memcpy(&wv, &w, 4);
  return __builtin_amdgcn_fdot2(wv, hv, acc, false);
#else
  __half2 hp = *reinterpret_cast<const __half2*>(&w);
  return acc + (float)hv[0]*__half2float(hp.x) + (float)hv[1]*__half2float(hp.y);
#endif
}

// ---------- agent-coherent (fence-free) access helpers ----------
DI unsigned cohld32(const void* p){
  return __hip_atomic_load((const unsigned*)p, __ATOMIC_RELAXED, __HIP_MEMORY_SCOPE_AGENT);
}
DI u64 cohld64(const void* p){
  return __hip_atomic_load((const u64*)p, __ATOMIC_RELAXED, __HIP_MEMORY_SCOPE_AGENT);
}
DI f4v cohldf4(const float* p){
  u64 lo = cohld64(p);
  u64 hi = cohld64(p + 2);
  f4v r;
  r[0]=__uint_as_float((unsigned)lo); r[1]=__uint_as_float((unsigned)(lo>>32));
  r[2]=__uint_as_float((unsigned)hi); r[3]=__uint_as_float((unsigned)(hi>>32));
  return r;
}
DI void cohst32(void* p, unsigned v){
  __hip_atomic_store((unsigned*)p, v, __ATOMIC_RELAXED, __HIP_MEMORY_SCOPE_AGENT);
}
DI void cohst64(void* p, u64 v){
  __hip_atomic_store((u64*)p, v, __ATOMIC_RELAXED, __HIP_MEMORY_SCOPE_AGENT);
}

// ---------- mega-builder: all independent precompute jobs in ONE launch ----------
// job block ranges (256 threads each):
//  J0 init       [0,638)       J1 hinit  [638,1022)    J2 enc->bf16 [1022,2046)
//  J3 Wq->f16pr  [2046,3070)   J4 wmT    [3070,3326)   J5 waT       [3326,3710)
//  J6 wxtpT      [3710,4030)   J7 wxaT   [4030,5566)   J8 buhT      [5566,6590)
//  J9 waA        [6590,7742)   J10 embg  [7742,8332)   J11 wfT      [8332,12588)
__global__ __launch_bounds__(256) void k_build(
    const float* __restrict__ bb, const float* __restrict__ eh, const float* __restrict__ ec,
    const int* __restrict__ dec, const float* __restrict__ enc, const float* __restrict__ emb,
    const float* __restrict__ Wx, const float* __restrict__ Uh, const float* __restrict__ Wm,
    const float* __restrict__ Wq, const float* __restrict__ Wa, const float* __restrict__ Wf,
    float* __restrict__ bp, float* __restrict__ h2X, float* __restrict__ cst,
    float* __restrict__ ctxX, unsigned* __restrict__ flags,
    u16* __restrict__ hhi, u16* __restrict__ hlo, u16* __restrict__ encB,
    u16* __restrict__ wq2, u16* __restrict__ wmT, u16* __restrict__ waT,
    u16* __restrict__ wxtpT, u16* __restrict__ wxaT, u16* __restrict__ buhT,
    u16* __restrict__ waA, u16* __restrict__ embB, u16* __restrict__ WfT){
  __shared__ u16 T[64*72];
  int lb = blockIdx.x, tid = threadIdx.x;
  if (lb < 638){                                   // J0: scalar init
    int i = lb*256 + tid;
    if (i < 2048) bp[i] = bb[ocol2(i)];
    else if (i < 2048+32768) h2X[i-2048] = eh[i-2048];
    else if (i < 2048+65536) cst[i-34816] = ec[i-34816];
    else if (i < 2048+131072) ctxX[i-67584] = 0.f;
    else if (i < 2048+131072+30208) flags[i-133120] = 0u;
  } else if (lb < 1022){                           // J1: hcat init (hi/lo)
    int i = (lb-638)*256 + tid; if (i >= 64*1536) return;
    int c = i % 1536;
    float f = (c < 512) ? eh[(i/1536)*512 + c] : 0.f;
    u16 hi = f2bf(f);
    hhi[i] = hi;
    hlo[i] = (c < 512) ? f2bf(f - bf2f(hi)) : (u16)0;
  } else if (lb < 2046){                           // J2: enc -> bf16
    int g = (lb-1022)*256 + tid; if (g >= 262144) return;
    const float4* p = (const float4*)(enc + (size_t)g*8);
    float4 a = p[0], b = p[1];
    u16 h[8] = {f2bf(a.x),f2bf(a.y),f2bf(a.z),f2bf(a.w),f2bf(b.x),f2bf(b.y),f2bf(b.z),f2bf(b.w)};
    *(uint4*)&encB[(size_t)g*8] = packh8(h);
  } else if (lb < 3070){                           // J3: Wq -> f16 pair-interleaved
    int g = (lb-2046)*256 + tid; if (g >= 262144) return;
    int h = g>>9, c = g&511;
    __half hf = __float2half(Wq[g]);
    wq2[(size_t)(h>>1)*1024 + (c<<1) + (h&1)] = *reinterpret_cast<u16*>(&hf);
  } else if (lb < 3326){                           // J4: Wm^T
    int g = (lb-3070)*256 + tid; if (g >= 512*128) return;
    int hcol = g/128, o = g%128;
    u16 h[8];
    #pragma unroll
    for(int j=0;j<8;++j){ int m = o*8+j; h[j]=f2bf(Wm[(size_t)m*512 + hcol]); }
    *(uint4*)&wmT[(size_t)hcol*1024 + o*8] = packh8(h);
  } else if (lb < 3710){                           // J5: Wa^T
    int g = (lb-3326)*256 + tid; if (g >= 512*192) return;
    int c = g/192, o = g%192;
    u16 h[8];
    #pragma unroll
    for(int j=0;j<8;++j){ int k = o*8+j; h[j]=f2bf(Wa[(size_t)k*512 + c]); }
    *(uint4*)&waT[(size_t)c*1536 + o*8] = packh8(h);
  } else if (lb < 4030){                           // J6: Wx top (slot cols)
    int g = (lb-3710)*256 + tid; if (g >= 2048*40) return;
    int pc = g/40, o = g%40; int oc = ocol2(pc);
    u16 h[8];
    #pragma unroll
    for(int j=0;j<8;++j){ int e = o*8+j; float f = (e<300)? Wx[(size_t)e*2048 + oc] : 0.f; h[j]=f2bf(f); }
    *(uint4*)&wxtpT[(size_t)pc*320 + o*8] = packh8(h);
  } else if (lb < 5566){                           // J7: Wx_att^T splits
    int g = (lb-4030)*256 + tid; if (g >= 2048*192) return;
    int pc = g/192, o = g%192; int oc = ocol(pc);
    u16 h[8];
    #pragma unroll
    for(int j=0;j<8;++j){
      int kp = o*8+j; int seg = kp>>9; int jd = kp&511;
      float f = Wx[(size_t)(300+jd)*2048 + oc];
      u16 hi = f2bf(f);
      h[j] = (seg==2) ? f2bf(f - bf2f(hi)) : hi;
    }
    *(uint4*)&wxaT[(size_t)pc*1536 + o*8] = packh8(h);
  } else if (lb < 6590){                           // J8: Uh^T splits
    int g = (lb-5566)*256 + tid; if (g >= 2048*128) return;
    int pc = g/128, o = g%128; int oc = ocol(pc);
    u16 h[8];
    #pragma unroll
    for(int j=0;j<8;++j){
      int kp = o*8+j; int r = kp&511;
      float f = Uh[(size_t)r*2048 + oc];
      u16 hi = f2bf(f);
      h[j] = (kp<512) ? hi : f2bf(f - bf2f(hi));
    }
    *(uint4*)&buhT[(size_t)pc*1024 + o*8] = packh8(h);
  } else if (lb < 7742){                           // J9: Wa splits (A side)
    int g = (lb-6590)*256 + tid; if (g >= 1536*192) return;
    int r = g/192, o = g%192;
    u16 h[8];
    #pragma unroll
    for(int j=0;j<8;++j){
      int kp = o*8+j; int seg = kp>>9; int jd = kp&511;
      float f = Wa[(size_t)r*512 + jd];
      u16 hi = f2bf(f);
      h[j] = (seg==1) ? f2bf(f - bf2f(hi)) : hi;
    }
    *(uint4*)&waA[(size_t)r*1536 + o*8] = packh8(h);
  } else if (lb < 8332){                           // J10: embedding gather
    int g = (lb-7742)*256 + tid; if (g >= 3776*40) return;
    int row = g/40, o = g%40;
    int b = row & 63, t = row >> 6;
    int tok = dec[b*59 + t];
    u16 h[8];
    #pragma unroll
    for(int j=0;j<8;++j){ int k = o*8+j; float f = (k<300)? emb[(size_t)tok*300 + k] : 0.f; h[j]=f2bf(f); }
    *(uint4*)&embB[(size_t)row*320 + o*8] = packh8(h);
  } else {                                         // J11: Wf transpose
    int lb2 = lb - 8332;
    int n0 = (lb2 % 532)*64, k0 = (lb2/532)*64;
    int kl = tid>>2, nq = (tid&3)*16;
    u16 h[16];
    if (n0 + 64 <= 34004){
      const float4* p = (const float4*)(Wf + (size_t)(k0+kl)*34004 + n0 + nq);
      #pragma unroll
      for(int q=0;q<4;++q){ float4 f = p[q]; h[q*4+0]=f2bf(f.x); h[q*4+1]=f2bf(f.y); h[q*4+2]=f2bf(f.z); h[q*4+3]=f2bf(f.w); }
    } else {
      #pragma unroll
      for(int j=0;j<16;++j){ int n = n0+nq+j; float f = (n<34004)? Wf[(size_t)(k0+kl)*34004 + n] : 0.f; h[j]=f2bf(f); }
    }
    *(uint4*)&T[kl*72 + nq] = packh8(h);
    *(uint4*)&T[kl*72 + nq + 8] = packh8(h+8);
    __syncthreads();
    int nl = tid>>2, kq = (tid&3)*16;
    int n = n0 + nl;
    if (n < 34004){
      u16 o[16];
      #pragma unroll
      for(int j=0;j<16;++j) o[j] = T[(kq+j)*72 + nl];
      *(uint4*)&WfT[(size_t)n*512 + k0 + kq]     = packh8(o);
      *(uint4*)&WfT[(size_t)n*512 + k0 + kq + 8] = packh8(o+8);
    }
  }
}

// (WzcT + Uh-on-top)^T splits: phys [hi(1536) | lo(1536)]
__global__ void k_wzcT(const float* __restrict__ wzcT, const float* __restrict__ Uh, u16* __restrict__ dst){
  int g = blockIdx.x*256 + threadIdx.x; if (g >= 2048*384) return;
  int pc = g/384, o = g%384; int oc = ocol(pc);
  u16 h[8];
  #pragma unroll
  for(int j=0;j<8;++j){
    int kp = o*8+j; int r = kp % 1536;
    float f = wzcT[(size_t)pc*1536 + r] + ((r<512) ? Uh[(size_t)r*2048 + oc] : 0.f);
    u16 hi = f2bf(f);
    h[j] = (kp<1536) ? hi : f2bf(f - bf2f(hi));
  }
  *(uint4*)&dst[(size_t)pc*3072 + o*8] = packh8(h);
}

// A2cat = [h2 | ctx] bf16, rows r = t*64+b  (reads slot t+1 == row r+64)
__global__ void k_a2dump(const float* __restrict__ h2X, const float* __restrict__ ctxX, u16* __restrict__ dst){
  int g = blockIdx.x*256 + threadIdx.x; if (g >= 3776*192) return;
  int r = g/192, o = g%192;
  u16 h[8];
  #pragma unroll
  for(int j=0;j<8;++j){
    int k = o*8+j;
    float f = (k<512) ? h2X[(size_t)(r+64)*512 + k] : ctxX[(size_t)(r+64)*1024 + (k-512)];
    h[j] = f2bf(f);
  }
  *(uint4*)&dst[(size_t)r*1536 + o*8] = packh8(h);
}

// ---------- 128x128 bf16 MFMA GEMM core (device fn):  C = A * Bt^T ----------
// EPI: 0 plain f32, 1 +bias f32, 2 bf16 out, 3 logits (bias + permuted store)
template<int EPI>
DI void gemm_dev(int bx, int by, u16* LSbuf,
    const u16* __restrict__ A, const u16* __restrict__ Bt,
    int M, int N, int K,
    float* __restrict__ Cf, u16* __restrict__ Cb,
    const float* __restrict__ bias, float* __restrict__ Cout){
  u16* Als = LSbuf;
  u16* Bls = LSbuf + 128*40;
  int tid = threadIdx.x;
  int c0 = bx*128, r0 = by*128;
  int wid = tid>>6, wr = wid>>1, wc = wid&1;
  int l15 = tid&15, l4 = (tid>>4)&3;
  f4v acc[4][4];
  #pragma unroll
  for(int m=0;m<4;++m)
  #pragma unroll
  for(int n=0;n<4;++n)
  #pragma unroll
  for(int i=0;i<4;++i) acc[m][n][i] = 0.f;

  int r = tid>>1, hf = tid&1;
  size_t arow = (size_t)min(r0 + r, M-1);
  size_t brow = (size_t)min(c0 + r, N-1);
  const u16* abase = A  + arow*K + hf*16;
  const u16* bbase = Bt + brow*K + hf*16;
  int nk = K >> 5;
  uint4 a0 = ((const uint4*)abase)[0], a1 = ((const uint4*)abase)[1];
  uint4 b0 = ((const uint4*)bbase)[0], b1 = ((const uint4*)bbase)[1];
  for (int ch=0; ch<nk; ++ch){
    __syncthreads();
    *(uint4*)&Als[r*40 + hf*16]     = a0;
    *(uint4*)&Als[r*40 + hf*16 + 8] = a1;
    *(uint4*)&Bls[r*40 + hf*16]     = b0;
    *(uint4*)&Bls[r*40 + hf*16 + 8] = b1;
    __syncthreads();
    if (ch+1 < nk){
      const uint4* ap = (const uint4*)(abase + (ch+1)*32);
      const uint4* bp = (const uint4*)(bbase + (ch+1)*32);
      a0 = ap[0]; a1 = ap[1]; b0 = bp[0]; b1 = bp[1];
    }
    s8v af[4], bfr[4];
    #pragma unroll
    for(int m=0;m<4;++m) af[m]  = *(const s8v*)&Als[(wr*64 + m*16 + l15)*40 + l4*8];
    #pragma unroll
    for(int n=0;n<4;++n) bfr[n] = *(const s8v*)&Bls[(wc*64 + n*16 + l15)*40 + l4*8];
    #pragma unroll
    for(int m=0;m<4;++m)
    #pragma unroll
    for(int n=0;n<4;++n)
      acc[m][n] = __builtin_amdgcn_mfma_f32_16x16x32_bf16(af[m], bfr[n], acc[m][n], 0,0,0);
  }
  // epilogue: LDS-staged transpose to full-line float4 stores
  __syncthreads();
  float* eps = ((float*)LSbuf) + wid*1024;   // 16 rows x 64 cols per wave
  #pragma unroll
  for(int m=0;m<4;++m){
    #pragma unroll
    for(int n=0;n<4;++n)
    #pragma unroll
    for(int i=0;i<4;++i)
      eps[(l4*4 + i)*64 + n*16 + l15] = acc[m][n][i];
    #pragma unroll
    for(int q=0;q<4;++q){
      int row = l4 + q*4;
      f4v v = *(const f4v*)&eps[row*64 + l15*4];
      int gr = r0 + wr*64 + m*16 + row;
      int gc = c0 + wc*64 + l15*4;
      if (gr < M && gc < N){
        if constexpr (EPI==0){
          *(f4v*)&Cf[(size_t)gr*N + gc] = v;
        } else if constexpr (EPI==1){
          f4v bv = *(const f4v*)&bias[gc];
          v += bv;
          *(f4v*)&Cf[(size_t)gr*N + gc] = v;
        } else if constexpr (EPI==2){
          unsigned p0 = ((unsigned)f2bf(v[1])<<16) | f2bf(v[0]);
          unsigned p1 = ((unsigned)f2bf(v[3])<<16) | f2bf(v[2]);
          uint2 pk; pk.x = p0; pk.y = p1;
          *(uint2*)&Cb[(size_t)gr*N + gc] = pk;
        } else {
          f4v bv = *(const f4v*)&bias[gc];
          v += bv;
          int b_ = gr&63, tt = gr>>6;
          *(f4v*)&Cout[((size_t)(b_*59 + tt))*34004 + gc] = v;
        }
      }
    }
  }
}

template<int EPI>
__global__ __launch_bounds__(256,2) void gemm_bf16(
    const u16* __restrict__ A, const u16* __restrict__ Bt,
    int M, int N, int K,
    float* __restrict__ Cf, u16* __restrict__ Cb,
    const float* __restrict__ bias, float* __restrict__ Cout){
  __shared__ u16 LSbuf[2*128*40];
  gemm_dev<EPI>(blockIdx.x, blockIdx.y, LSbuf, A, Bt, M, N, K, Cf, Cb, bias, Cout);
}

// merged precompute GEMMs: Zemb(480) + keys(64) + WzcT(192) in one launch
__global__ __launch_bounds__(256,2) void k_gemm3(
    const u16* __restrict__ embB, const u16* __restrict__ wxtpT, float* __restrict__ Zemb,
    const float* __restrict__ bp,
    const u16* __restrict__ encB, const u16* __restrict__ wmT, float* __restrict__ keys,
    const u16* __restrict__ wxaT, const u16* __restrict__ waA, float* __restrict__ wzc){
  __shared__ u16 LSbuf[2*128*40];
  int b = blockIdx.x;
  if (b < 480){
    gemm_dev<1>(b%16, b/16, LSbuf, embB, wxtpT, 3776, 2048, 320, Zemb, nullptr, bp, nullptr);
  } else if (b < 544){
    int b2 = b-480;
    gemm_dev<0>(b2%4, b2/4, LSbuf, encB, wmT, 2048, 512, 1024, keys, nullptr, nullptr, nullptr);
  } else {
    int b3 = b-544;
    gemm_dev<0>(b3%12, b3/12, LSbuf, wxaT, waA, 2048, 1536, 1536, wzc, nullptr, nullptr, nullptr);
  }
}

// ---------- fused per-step kernel: z-GEMM + aggregator-sync + LSTM/attention ----------
// (structure identical to round-8 proven version; q-GEMV now f16 dot2 on wq2,
//  ctx reads bf16 encB)
__global__ __launch_bounds__(512,4) void step_fused(
    int t,
    const u16* __restrict__ wzT, const u16* __restrict__ buhT,
    u16* __restrict__ hhi, u16* __restrict__ hlo,
    float* __restrict__ zparts, const float* __restrict__ Zemb,
    float* __restrict__ cst, float* __restrict__ h2X, float* __restrict__ ctxX,
    const u16* __restrict__ wq2, const float* __restrict__ keys,
    const u16* __restrict__ encB, const float* __restrict__ vv,
    unsigned* __restrict__ flags){
  __shared__ float smem[16384];   // 64 KB
  int bid = blockIdx.x, tid = threadIdx.x;
  unsigned* flg = flags + (size_t)t*512;
  int variant = (t==0) ? 0 : 1;

  if (bid < 256){
    // ---- z-GEMM block ----
    int sl = bid>>6, cg = bid&63;
    int pc0 = cg*32;
    int wv = tid>>6, lane = tid&63;
    int l15 = lane&15, l4 = lane>>4;
    const u16* Bt = variant ? wzT : buhT;
    int physK = variant ? 3072 : 1024;
    int CS = variant ? 36 : 12;        // K-chunks per slice (virtualK/32/4)
    int ck0 = sl*CS, ck1 = ck0 + CS;

    f4v acc[4][2];
    #pragma unroll
    for(int m=0;m<4;++m)
    #pragma unroll
    for(int n=0;n<2;++n)
    #pragma unroll
    for(int i=0;i<4;++i) acc[m][n][i] = 0.f;

    for (int c = ck0 + wv; c < ck1; c += 8){
      int k1 = c*32;
      const u16* ap; int inner, kB;
      if (variant==0){
        inner = k1 & 511;
        ap = ((((k1>>9)&3)==1) ? hlo : hhi);
        kB = (k1 < 1024) ? (k1 & 511) : (k1 - 512);
      } else {
        int sg = k1/1536; inner = k1 - sg*1536;
        ap = (sg==1) ? hlo : hhi;
        kB = (k1 < 3072) ? (k1 % 1536) : (1536 + (k1 - 3072));
      }
      uint4 av[4], bv[2];
      #pragma unroll
      for(int m=0;m<4;++m)
        av[m] = *(const uint4*)(ap + (size_t)(m*16 + l15)*1536 + inner + l4*8);
      #pragma unroll
      for(int n=0;n<2;++n)
        bv[n] = *(const uint4*)(Bt + (size_t)(pc0 + n*16 + l15)*physK + kB + l4*8);
      #pragma unroll
      for(int m=0;m<4;++m){
        s8v am = u4s8(av[m]);
        #pragma unroll
        for(int n=0;n<2;++n)
          acc[m][n] = __builtin_amdgcn_mfma_f32_16x16x32_bf16(am, u4s8(bv[n]), acc[m][n], 0,0,0);
      }
    }
    // LDS reduce across the 8 K-interleaved waves
    float* red = smem + wv*2048;
    #pragma unroll
    for(int m=0;m<4;++m)
    #pragma unroll
    for(int n=0;n<2;++n)
    #pragma unroll
    for(int i=0;i<4;++i)
      red[(m*16 + l4*4 + i)*32 + n*16 + l15] = acc[m][n][i];
    __syncthreads();

    int rr = tid>>3, cq = (tid&7)*4;
    f4v s = *(const f4v*)&smem[rr*32 + cq];
    #pragma unroll
    for(int w=1;w<8;++w)
      s += *(const f4v*)&smem[w*2048 + rr*32 + cq];
    float* zp = zparts + (size_t)sl*131072 + (size_t)rr*2048 + pc0 + cq;
    cohst64(&zp[0], (u64)__float_as_uint(s[0]) | ((u64)__float_as_uint(s[1])<<32));
    cohst64(&zp[2], (u64)__float_as_uint(s[2]) | ((u64)__float_as_uint(s[3])<<32));
    asm volatile("s_waitcnt vmcnt(0)" ::: "memory");
    __syncthreads();
    if (tid==0) cohst32(&flg[bid], 1u);

  } else {
    // ---- attention block (one per batch) ----
    int b = bid - 256;
    // prefetch step-t inputs that do NOT depend on z (hides latency under wait)
    int j = tid;
    int base = (j>>3)*32 + (j&7)*4;            // gate-slot base for unit j
    f4v ze = *(const f4v*)&Zemb[(size_t)t*131072 + (size_t)b*2048 + base];
    float cprev = cst[(size_t)b*512 + j];
    float vvj = vv[j];
    // sync: b0 aggregates 256 flags, publishes one done word; others poll it
    if (b == 0){
      if (tid < 256){
        while (cohld32(&flg[tid]) == 0u) __builtin_amdgcn_s_sleep(2);
      }
      __syncthreads();
      if (tid==0) cohst32(&flg[511], 1u);
    } else {
      if (tid==0){
        while (cohld32(&flg[511]) == 0u) __builtin_amdgcn_s_sleep(1);
      }
      __syncthreads();
    }
    asm volatile("" ::: "memory");

    float* zl  = smem;            // 2048
    float* h2s = smem + 2048;     // 512
    float* vs2 = smem + 2560;     // 512
    float* qs  = smem + 3072;     // 512
    float* qpl = smem + 3584;     // 4096
    float* scl = smem + 7680;     // 32
    float* alw = smem + 7712;     // 32
    // z-sum gather (coherent, 4-deep) + LDS slot-scatter
    {
      int p4 = tid*4;
      f4v z0; z0[0]=0.f; z0[1]=0.f; z0[2]=0.f; z0[3]=0.f;
      #pragma unroll
      for(int s2=0; s2<4; ++s2)
        z0 += cohldf4(&zparts[(size_t)s2*131072 + (size_t)b*2048 + p4]);
      #pragma unroll
      for(int e=0;e<4;++e)
        zl[pc2slot(p4+e)] = z0[e];
    }
    __syncthreads();
    // LSTM: one unit per thread
    {
      f4v s4 = ze + *(const f4v*)&zl[base];
      float c2 = sigm(s4[1])*cprev + sigm(s4[0])*tanhx(s4[2]);
      float h2 = sigm(s4[3])*tanhx(c2);
      cst[(size_t)b*512 + j] = c2;
      h2X[(size_t)(t+1)*32768 + (size_t)b*512 + j] = h2;
      h2s[j] = h2; vs2[j] = vvj;
      u16 hh2 = f2bf(h2);
      hhi[(size_t)b*1536 + j] = hh2;
      hlo[(size_t)b*1536 + j] = f2bf(h2 - bf2f(hh2));
    }
    __syncthreads();
    // q = h2 @ Wq : f16 pair-interleaved wq2, v_dot2 (8 h-slices x 64 thr x 8 cols)
    {
      int c8 = (tid&63)*8, hs = tid>>6;
      float qp[8] = {0,0,0,0,0,0,0,0};
      const u16* wp = wq2 + (size_t)(hs*32)*1024 + c8*2;
      #pragma unroll 4
      for(int i=0;i<32;++i){
        int hp = hs*32 + i;
        f16x2 hv; hv[0] = (_Float16)h2s[2*hp]; hv[1] = (_Float16)h2s[2*hp+1];
        uint4 w0 = *(const uint4*)wp;
        uint4 w1 = *(const uint4*)(wp + 8);
        wp += 1024;
        qp[0]=qdot(w0.x,hv,qp[0]); qp[1]=qdot(w0.y,hv,qp[1]);
        qp[2]=qdot(w0.z,hv,qp[2]); qp[3]=qdot(w0.w,hv,qp[3]);
        qp[4]=qdot(w1.x,hv,qp[4]); qp[5]=qdot(w1.y,hv,qp[5]);
        qp[6]=qdot(w1.z,hv,qp[6]); qp[7]=qdot(w1.w,hv,qp[7]);
      }
      *(float4*)&qpl[hs*512 + c8]     = make_float4(qp[0],qp[1],qp[2],qp[3]);
      *(float4*)&qpl[hs*512 + c8 + 4] = make_float4(qp[4],qp[5],qp[6],qp[7]);
    }
    __syncthreads();
    { float s = 0.f; for(int hs=0; hs<8; ++hs) s += qpl[hs*512 + tid]; qs[tid] = s; }
    __syncthreads();
    // scores: 16 threads per s (32 s), 32 h each, float4 keys
    {
      int s = tid>>4, hh = tid&15;
      const float4* kb4 = (const float4*)(keys + ((size_t)(b*32 + s))*512 + hh*32);
      float part = 0.f;
      #pragma unroll
      for(int i8=0;i8<8;++i8){
        float4 kv = kb4[i8];
        int h = hh*32 + i8*4;
        part += vs2[h+0]*tanhx(kv.x + qs[h+0]);
        part += vs2[h+1]*tanhx(kv.y + qs[h+1]);
        part += vs2[h+2]*tanhx(kv.z + qs[h+2]);
        part += vs2[h+3]*tanhx(kv.w + qs[h+3]);
      }
      #pragma unroll
      for(int m=1;m<16;m<<=1) part += __shfl_xor(part, m, 64);
      if (hh==0) scl[s] = part;
    }
    __syncthreads();
    // softmax over 32
    if (tid < 32){
      float sc = scl[tid];
      float mx = sc;
      #pragma unroll
      for(int m=1;m<32;m<<=1) mx = fmaxf(mx, __shfl_xor(mx, m, 64));
      float e = __expf(sc - mx);
      float sm = e;
      #pragma unroll
      for(int m=1;m<32;m<<=1) sm += __shfl_xor(sm, m, 64);
      alw[tid] = e/sm;
    }
    __syncthreads();
    // ctx: 2 adjacent cols per thread, bf16 encB loads (4B/iter)
    {
      const u16* eb = encB + (size_t)b*32768;
      int cc = tid*2;
      float c0 = 0.f, c1 = 0.f;
      for(int s=0;s<32;++s){
        float al = alw[s];
        unsigned ev = *(const unsigned*)&eb[(size_t)s*1024 + cc];
        c0 += al*bf2f((u16)(ev&0xffffu));
        c1 += al*bf2f((u16)(ev>>16));
      }
      float2 co; co.x = c0; co.y = c1;
      *(float2*)&ctxX[(size_t)(t+1)*65536 + (size_t)b*1024 + cc] = co;
      u16 x0 = f2bf(c0), x1 = f2bf(c1);
      *(unsigned*)&hhi[(size_t)b*1536 + 512 + cc] = (unsigned)x0 | ((unsigned)x1<<16);
      u16 y0 = f2bf(c0 - bf2f(x0)), y1 = f2bf(c1 - bf2f(x1));
      *(unsigned*)&hlo[(size_t)b*1536 + 512 + cc] = (unsigned)y0 | ((unsigned)y1<<16);
    }
  }
}

// ---------- host ----------
extern "C" void kernel_launch(void* const* d_in, const int* in_sizes, int n_in,
                              void* d_out, int out_size, void* d_ws, size_t ws_size,
                              hipStream_t stream){
  const int*   dec = (const int*)d_in[0];
  const float* enc = (const float*)d_in[1];
  const float* eh  = (const float*)d_in[2];
  const float* ec  = (const float*)d_in[3];
  const float* emb = (const float*)d_in[4];
  const float* Wx  = (const float*)d_in[5];
  const float* Uh  = (const float*)d_in[6];
  const float* bb  = (const float*)d_in[7];
  const float* Wm  = (const float*)d_in[8];
  const float* Wq  = (const float*)d_in[9];
  const float* vv  = (const float*)d_in[10];
  const float* Wa  = (const float*)d_in[11];
  const float* Wf  = (const float*)d_in[12];
  const float* bf  = (const float*)d_in[13];
  float* out = (float*)d_out;

  // ---- workspace carving ----
  char* w = (char*)d_ws; size_t off = 0;
  auto alloc = [&](size_t bytes)->char*{ char* p = w + off; off = (off + bytes + 255) & ~(size_t)255; return p; };
  u16* WfT   = (u16*)alloc((size_t)34004*512*2);
  u16* attn2 = (u16*)alloc((size_t)3776*512*2);
  size_t liveEnd = off;
  const size_t needB = (size_t)131<<20;
  bool fits = (ws_size >= liveEnd + needB);
  char* wb = fits ? (w + liveEnd) : (char*)d_out;
  size_t offb = 0;
  auto allocB = [&](size_t bytes)->char*{ char* p = wb + offb; offb = (offb + bytes + 255) & ~(size_t)255; return p; };

  u16* wzT   = (u16*)allocB((size_t)2048*3072*2);
  u16* buhT  = (u16*)allocB((size_t)2048*1024*2);
  u16* wq2   = (u16*)allocB((size_t)512*512*2);
  u16* waT   = (u16*)allocB((size_t)512*1536*2);
  u16* wmT   = (u16*)allocB((size_t)512*1024*2);
  u16* wxtpT = (u16*)allocB((size_t)2048*320*2);
  u16* wxaT  = (u16*)allocB((size_t)2048*1536*2);
  u16* waA   = (u16*)allocB((size_t)1536*1536*2);
  float* wzc = (float*)allocB((size_t)2048*1536*4);
  u16* embB  = (u16*)allocB((size_t)3776*320*2);
  u16* encB  = (u16*)allocB((size_t)2048*1024*2);
  float* Zemb  = (float*)allocB((size_t)3776*2048*4);
  float* keys  = (float*)allocB((size_t)2048*512*4);
  float* zparts= (float*)allocB((size_t)9*64*2048*4);
  float* h2X   = (float*)allocB((size_t)60*64*512*4);
  float* ctxX  = (float*)allocB((size_t)60*64*1024*4);
  float* cst   = (float*)allocB((size_t)64*512*4);
  float* bp    = (float*)allocB((size_t)2048*4);
  u16* A2c   = (u16*)allocB((size_t)3776*1536*2);
  u16* hhi   = (u16*)allocB((size_t)64*1536*2);
  u16* hlo   = (u16*)allocB((size_t)64*1536*2);
  unsigned* flags = (unsigned*)allocB((size_t)59*512*4);

  // ---- precompute: ONE mega-builder launch ----
  k_build<<<12588,256,0,stream>>>(bb, eh, ec, dec, enc, emb, Wx, Uh, Wm, Wq, Wa, Wf,
                                  bp, h2X, cst, ctxX, flags,
                                  hhi, hlo, encB, wq2, wmT, waT,
                                  wxtpT, wxaT, buhT, waA, embB, WfT);

  // merged GEMMs: Zemb + keys + WzcT
  k_gemm3<<<736,256,0,stream>>>(embB, wxtpT, Zemb, bp, encB, wmT, keys, wxaT, waA, wzc);
  // W'z^T = split( WzcT + Uh(top) )^T   [2048][3072]
  k_wzcT<<<(2048*384+255)/256,256,0,stream>>>(wzc, Uh, wzT);

  // ---- recurrence: ONE fused launch per step ----
  for (int t=0; t<59; ++t){
    step_fused<<<320,512,0,stream>>>(t, wzT, buhT, hhi, hlo, zparts, Zemb,
                                     cst, h2X, ctxX, wq2, keys, encB, vv, flags);
  }

  // ---- deferred attn2 + logits ----
  k_a2dump<<<(3776*192+255)/256,256,0,stream>>>(h2X, ctxX, A2c);
  gemm_bf16<2><<<dim3(4,30),256,0,stream>>>(A2c, waT, 3776, 512, 1536, nullptr, attn2, nullptr, nullptr);
  gemm_bf16<3><<<dim3(266,30),256,0,stream>>>(attn2, WfT, 3776, 34004, 512, nullptr, nullptr, bf, out);
}